// Round 17
// baseline (474.460 us; speedup 1.0000x reference)
//
#include <hip/hip_runtime.h>
#include <hip/hip_bf16.h>
#include <stdint.h>

typedef __bf16 bf16;
typedef bf16 bf16x8 __attribute__((ext_vector_type(8)));
typedef bf16 bf16x4 __attribute__((ext_vector_type(4)));
typedef float f32x4 __attribute__((ext_vector_type(4)));

#define MFMA16(a, b, c) __builtin_amdgcn_mfma_f32_16x16x32_bf16((a), (b), (c), 0, 0, 0)
#define QKSWZ(n) ((((n) >> 2) & 3) << 3)
#define LGKM0() do { asm volatile("s_waitcnt lgkmcnt(0)" ::: "memory"); \
                     __builtin_amdgcn_sched_barrier(0); } while (0)

// ---- k0: x [B,C,H,W] fp32 -> xT [B,H,W,C] bf16 linear (tiled LDS transpose) ----
__global__ __launch_bounds__(256) void tin_kernel(const float* __restrict__ x,
                                                  bf16* __restrict__ xT)
{
    __shared__ float s[128 * 65];
    const int blk = blockIdx.x;            // b*1024 + pxchunk
    const int b = blk >> 10;
    const int px0 = (blk & 1023) * 64;
    const int tid = threadIdx.x;
    {
        int c0 = tid >> 6, pxl = tid & 63;
        const float* src = x + (size_t)b * 8388608 + px0 + pxl;
#pragma unroll
        for (int i = 0; i < 32; ++i) {
            int c = c0 + i * 4;
            s[c * 65 + pxl] = src[(size_t)c * 65536];
        }
    }
    __syncthreads();
    int px = tid >> 2, piece = tid & 3;
    bf16* dstp = xT + ((size_t)b * 65536 + px0 + px) * 128;
#pragma unroll
    for (int k = 0; k < 4; ++k) {
        bf16x8 v8;
        int cb = (k * 4 + piece) * 8;
#pragma unroll
        for (int j = 0; j < 8; ++j) v8[j] = (bf16)s[(cb + j) * 65 + px];
        *(bf16x8*)(dstp + cb) = v8;
    }
}

// ---- convert+transpose weights to bf16 + precompute per-lane bias fragments ----
// biasC[h*4096 + i*512 + lane*8 + s]: bias for softmax element e=i*8+s of lane,
// head h, in the sacc fragment order (e = (mt*4+nt)*4+r). Same for all windows.
__global__ void wconv_kernel(const float* __restrict__ w_qkv,
                             const float* __restrict__ w_proj,
                             const float* __restrict__ rpb,
                             bf16* __restrict__ wqkvT,
                             bf16* __restrict__ wprojT,
                             bf16* __restrict__ biasC)
{
    int id = blockIdx.x * 256 + threadIdx.x;
    if (id < 16384) {
        int s = id & 7, lane = (id >> 3) & 63, i = (id >> 9) & 7, h = id >> 12;
        int e = i * 8 + s;
        int mt = e >> 4, nt = (e >> 2) & 3, r = e & 3;
        int n = nt * 16 + (lane & 15);
        int m = mt * 16 + (lane >> 4) * 4 + r;
        int rel = ((n >> 3) - (m >> 3) + 7) * 15 + ((n & 7) - (m & 7) + 7);
        biasC[id] = (bf16)rpb[rel * 4 + h];
    }
    if (id < 49152) {                       // 384*128
        int co = id >> 7, c = id & 127;
        wqkvT[id] = (bf16)w_qkv[c * 384 + co];
    } else {
        int id2 = id - 49152;               // 128*128
        int co = id2 >> 7, c = id2 & 127;
        wprojT[id2] = (bf16)w_proj[c * 128 + co];
    }
}

// ---- fused window/grid relative attention, one 8x8 window per block ----
// Own-head decomposition, 3-pass QKV (q,k,v; 2 tiles each, immediate flush).
// Per-wave 4KB exchange quarters (q->k->P halves in s_ex; vT in s_x quarter).
// 4 block barriers; direct-register epilogue; precomputed bias fragments.
// LDS 32KB, launch_bounds(256,5): 5 blocks/CU = 160KB LDS exactly, VGPR<=102.
// NOTE (R15 lesson): multi-window sequential loops per block regress badly.
// STAGE 0: window partition; in = xT linear, out = x1T grid-major (scatter)
// STAGE 1: grid partition; in/out grid-major CONTIG 16KB + pooling partials
template<int STAGE>
__global__ __launch_bounds__(256, 5)
void attn_kernel(const bf16* __restrict__ xin, bf16* __restrict__ xout,
                 const bf16* __restrict__ wqkvT, const bf16* __restrict__ wprojT,
                 const float* __restrict__ b_qkv, const float* __restrict__ b_proj,
                 const bf16* __restrict__ biasC,
                 float* __restrict__ psum, float* __restrict__ pmax)
{
    __shared__ __align__(16) bf16 s_x[8192];   // input [n][c] -> vT quarters -> attnout
    __shared__ __align__(16) bf16 s_ex[8192];  // per-wave 4KB: q -> k -> P halves

    const int tid = threadIdx.x;
    const int lane = tid & 63;
    const int wv = tid >> 6;     // wave = head
    const int lr = lane & 15;
    const int lg = lane >> 4;
    bf16* exq = s_ex + wv * 2048;              // per-wave exchange quarter
    bf16* exv = s_x + wv * 2048;               // per-wave vT quarter (valid after B2)

    const int blk = (blockIdx.x & 7) * 512 + (blockIdx.x >> 3);  // XCD-bijective
    const int b  = blk >> 10;
    const int wr = (blk >> 5) & 31;
    const int wc = blk & 31;

    // ---- stage input window into LDS ----
    if constexpr (STAGE == 0) {
        int n = tid >> 2, piece = tid & 3;
        int ph = wr * 8 + (n >> 3), pw = wc * 8 + (n & 7);
        const bf16* src = xin + ((size_t)b * 65536 + (size_t)ph * 256 + pw) * 128;
#pragma unroll
        for (int k = 0; k < 4; ++k) {
            int cc = (k * 4 + piece) * 8;
            bf16x8 v = *(const bf16x8*)(src + cc);
            *(bf16x8*)&s_x[(n * 128 + cc) ^ ((n & 15) << 3)] = v;
        }
    } else {
        const bf16* src = xin + ((size_t)b * 65536 + (size_t)(wr * 32 + wc) * 64) * 128;
#pragma unroll
        for (int k = 0; k < 4; ++k) {
            int g = k * 256 + tid;
            int n = g >> 4, cc = (g & 15) * 8;
            bf16x8 v = *(const bf16x8*)(src + g * 8);
            *(bf16x8*)&s_x[(n * 128 + cc) ^ ((n & 15) << 3)] = v;
        }
    }

    __syncthreads();   // B1

    // ---- pass Q: 2 tiles, scatter to exq, fragments to regs ----
    bf16x8 qb[4];
    {
        f32x4 acc[4][2];
#pragma unroll
        for (int mt = 0; mt < 4; ++mt)
#pragma unroll
            for (int t = 0; t < 2; ++t) acc[mt][t] = (f32x4){0.f, 0.f, 0.f, 0.f};
        bf16x8 wB[2][4];
#pragma unroll
        for (int t = 0; t < 2; ++t) {
            int co = wv * 32 + t * 16 + lr;
            const bf16* rp = wqkvT + co * 128 + lg * 8;
#pragma unroll
            for (int ks = 0; ks < 4; ++ks) wB[t][ks] = *(const bf16x8*)(rp + ks * 32);
        }
#pragma unroll
        for (int ks = 0; ks < 4; ++ks) {
            bf16x8 a[4];
#pragma unroll
            for (int mt = 0; mt < 4; ++mt) {
                int n = mt * 16 + lr;
                a[mt] = *(const bf16x8*)&s_x[(n * 128 + ks * 32 + lg * 8) ^ ((n & 15) << 3)];
            }
#pragma unroll
            for (int mt = 0; mt < 4; ++mt)
#pragma unroll
                for (int t = 0; t < 2; ++t)
                    acc[mt][t] = MFMA16(a[mt], wB[t][ks], acc[mt][t]);
        }
#pragma unroll
        for (int t = 0; t < 2; ++t) {
            float bias = b_qkv[wv * 32 + t * 16 + lr];
            int d = t * 16 + lr;
#pragma unroll
            for (int mt = 0; mt < 4; ++mt) {
                int n0 = mt * 16 + lg * 4;
#pragma unroll
                for (int r = 0; r < 4; ++r) {
                    int n = n0 + r;
                    exq[n * 32 + (d ^ QKSWZ(n))] = (bf16)(acc[mt][t][r] + bias);
                }
            }
        }
        LGKM0();
#pragma unroll
        for (int t = 0; t < 4; ++t) {
            int m = t * 16 + lr;
            qb[t] = *(const bf16x8*)&exq[m * 32 + ((lg * 8) ^ QKSWZ(m))];
        }
        LGKM0();   // qb landed before k overwrites quarter
    }

    // ---- pass K: 2 tiles, scatter to exq ----
    {
        f32x4 acc[4][2];
#pragma unroll
        for (int mt = 0; mt < 4; ++mt)
#pragma unroll
            for (int t = 0; t < 2; ++t) acc[mt][t] = (f32x4){0.f, 0.f, 0.f, 0.f};
        bf16x8 wB[2][4];
#pragma unroll
        for (int t = 0; t < 2; ++t) {
            int co = 128 + wv * 32 + t * 16 + lr;
            const bf16* rp = wqkvT + co * 128 + lg * 8;
#pragma unroll
            for (int ks = 0; ks < 4; ++ks) wB[t][ks] = *(const bf16x8*)(rp + ks * 32);
        }
#pragma unroll
        for (int ks = 0; ks < 4; ++ks) {
            bf16x8 a[4];
#pragma unroll
            for (int mt = 0; mt < 4; ++mt) {
                int n = mt * 16 + lr;
                a[mt] = *(const bf16x8*)&s_x[(n * 128 + ks * 32 + lg * 8) ^ ((n & 15) << 3)];
            }
#pragma unroll
            for (int mt = 0; mt < 4; ++mt)
#pragma unroll
                for (int t = 0; t < 2; ++t)
                    acc[mt][t] = MFMA16(a[mt], wB[t][ks], acc[mt][t]);
        }
#pragma unroll
        for (int t = 0; t < 2; ++t) {
            float bias = b_qkv[128 + wv * 32 + t * 16 + lr];
            int d = t * 16 + lr;
#pragma unroll
            for (int mt = 0; mt < 4; ++mt) {
                int n0 = mt * 16 + lg * 4;
#pragma unroll
                for (int r = 0; r < 4; ++r) {
                    int n = n0 + r;
                    exq[n * 32 + (d ^ QKSWZ(n))] = (bf16)(acc[mt][t][r] + bias);
                }
            }
        }
    }

    // residual -> registers (before s_x quarters get overwritten by vT)
    bf16x4 resr[2][4];
#pragma unroll
    for (int ct = 0; ct < 2; ++ct)
#pragma unroll
        for (int nt = 0; nt < 4; ++nt) {
            int n = nt * 16 + lr;
            int c0 = wv * 32 + ct * 16 + lg * 4;
            resr[ct][nt] = *(const bf16x4*)&s_x[(n * 128 + c0) ^ ((n & 15) << 3)];
        }

    // ---- pass V: 2 tiles (held briefly), flush to s_x quarter after B2 ----
    f32x4 accV[4][2];
    {
#pragma unroll
        for (int mt = 0; mt < 4; ++mt)
#pragma unroll
            for (int t = 0; t < 2; ++t) accV[mt][t] = (f32x4){0.f, 0.f, 0.f, 0.f};
        bf16x8 wB[2][4];
#pragma unroll
        for (int t = 0; t < 2; ++t) {
            int co = 256 + wv * 32 + t * 16 + lr;
            const bf16* rp = wqkvT + co * 128 + lg * 8;
#pragma unroll
            for (int ks = 0; ks < 4; ++ks) wB[t][ks] = *(const bf16x8*)(rp + ks * 32);
        }
#pragma unroll
        for (int ks = 0; ks < 4; ++ks) {
            bf16x8 a[4];
#pragma unroll
            for (int mt = 0; mt < 4; ++mt) {
                int n = mt * 16 + lr;
                a[mt] = *(const bf16x8*)&s_x[(n * 128 + ks * 32 + lg * 8) ^ ((n & 15) << 3)];
            }
#pragma unroll
            for (int mt = 0; mt < 4; ++mt)
#pragma unroll
                for (int t = 0; t < 2; ++t)
                    accV[mt][t] = MFMA16(a[mt], wB[t][ks], accV[mt][t]);
        }
    }

    // bias fragments -> registers (coalesced 16B loads, L1-hot; overlap w/ MFMA)
    bf16x8 bi[8];
    {
        const bf16* bpp = biasC + wv * 4096 + lane * 8;
#pragma unroll
        for (int i = 0; i < 8; ++i)
            bi[i] = *(const bf16x8*)(bpp + i * 512);
    }

    __syncthreads();   // B2: all s_x GEMM/residual reads done; quarters free

    // vT scatter -> own s_x quarter [d][64] swz (frees accV before softmax)
#pragma unroll
    for (int t = 0; t < 2; ++t) {
        float bias = b_qkv[256 + wv * 32 + t * 16 + lr];
        int d = t * 16 + lr;
#pragma unroll
        for (int mt = 0; mt < 4; ++mt) {
            bf16x4 v4;
#pragma unroll
            for (int r = 0; r < 4; ++r) v4[r] = (bf16)(accV[mt][t][r] + bias);
            int idx = (d * 64 + mt * 16 + lg * 4) ^ ((d & 7) << 3);
            *(bf16x4*)&exv[idx] = v4;
        }
    }

    // ---- S^T = K * Q^T (wave-local) ----
    f32x4 sacc[4][4];
#pragma unroll
    for (int mt = 0; mt < 4; ++mt)
#pragma unroll
        for (int nt = 0; nt < 4; ++nt) sacc[mt][nt] = (f32x4){0.f, 0.f, 0.f, 0.f};
#pragma unroll
    for (int mt = 0; mt < 4; ++mt) {
        int m = mt * 16 + lr;
        bf16x8 ka = *(const bf16x8*)&exq[m * 32 + ((lg * 8) ^ QKSWZ(m))];
#pragma unroll
        for (int nt = 0; nt < 4; ++nt)
            sacc[mt][nt] = MFMA16(ka, qb[nt], sacc[mt][nt]);
    }

    // softmax over m (scale 0.5 + precomputed bias fragment, pure FMA)
    float inv[4];
#pragma unroll
    for (int nt = 0; nt < 4; ++nt) {
        float mx = -1e30f;
#pragma unroll
        for (int mt = 0; mt < 4; ++mt)
#pragma unroll
            for (int r = 0; r < 4; ++r) {
                int e = (mt * 4 + nt) * 4 + r;
                float lgt = sacc[mt][nt][r] * 0.5f + (float)bi[e >> 3][e & 7];
                sacc[mt][nt][r] = lgt;
                mx = fmaxf(mx, lgt);
            }
        mx = fmaxf(mx, __shfl_xor(mx, 16));
        mx = fmaxf(mx, __shfl_xor(mx, 32));
        float sum = 0.f;
#pragma unroll
        for (int mt = 0; mt < 4; ++mt)
#pragma unroll
            for (int r = 0; r < 4; ++r) {
                float p = __expf(sacc[mt][nt][r] - mx);
                sacc[mt][nt][r] = p;
                sum += p;
            }
        sum += __shfl_xor(sum, 16);
        sum += __shfl_xor(sum, 32);
        inv[nt] = 1.f / sum;
    }
    LGKM0();   // ka reads + vT stores landed

    // v fragments -> registers
    bf16x8 va[2][2];
#pragma unroll
    for (int dt = 0; dt < 2; ++dt) {
        int d = dt * 16 + lr;
#pragma unroll
        for (int ks = 0; ks < 2; ++ks)
            va[dt][ks] = *(const bf16x8*)&exv[(d * 64 + ks * 32 + lg * 8) ^ ((d & 7) << 3)];
    }

    __syncthreads();   // B3: all waves' va preloads done -> s_x fully dead

    // ---- PV via P halves through exq: out^T[d][n] ----
    f32x4 oacc[2][4];
#pragma unroll
    for (int dt = 0; dt < 2; ++dt)
#pragma unroll
        for (int nt = 0; nt < 4; ++nt) oacc[dt][nt] = (f32x4){0.f, 0.f, 0.f, 0.f};
#pragma unroll
    for (int ks = 0; ks < 2; ++ks) {
#pragma unroll
        for (int nt = 0; nt < 4; ++nt) {
            int n = nt * 16 + lr;
#pragma unroll
            for (int mh = 0; mh < 2; ++mh) {
                int mt = ks * 2 + mh;
                bf16x4 v4;
#pragma unroll
                for (int r = 0; r < 4; ++r) v4[r] = (bf16)(sacc[mt][nt][r] * inv[nt]);
                int off = (mh * 16 + lg * 4) ^ ((n & 3) << 3);
                *(bf16x4*)&exq[n * 32 + off] = v4;
            }
        }
        LGKM0();
        bf16x8 pb[4];
#pragma unroll
        for (int nt = 0; nt < 4; ++nt) {
            int n = nt * 16 + lr;
            pb[nt] = *(const bf16x8*)&exq[n * 32 + ((lg * 8) ^ ((n & 3) << 3))];
        }
#pragma unroll
        for (int dt = 0; dt < 2; ++dt)
#pragma unroll
            for (int nt = 0; nt < 4; ++nt)
                oacc[dt][nt] = MFMA16(va[dt][ks], pb[nt], oacc[dt][nt]);
        LGKM0();   // pb reads landed before next half overwrites
    }

    // attn output -> s_x as [n][c] (safe: B3 passed; exq is wave-local)
#pragma unroll
    for (int dt = 0; dt < 2; ++dt)
#pragma unroll
        for (int nt = 0; nt < 4; ++nt) {
            int n = nt * 16 + lr;
            int c0 = wv * 32 + dt * 16 + lg * 4;
            bf16x4 v4;
#pragma unroll
            for (int r = 0; r < 4; ++r) v4[r] = (bf16)oacc[dt][nt][r];
            int idx = (n * 128 + c0) ^ ((n & 15) << 3);
            *(bf16x4*)&s_x[idx] = v4;
        }

    __syncthreads();   // B4: attnout complete

    // ---- proj: x1^T[co][n] = sum_c wproj[c][co] * attn[n][c] ----
    f32x4 pacc[2][4];
#pragma unroll
    for (int ct = 0; ct < 2; ++ct)
#pragma unroll
        for (int nt = 0; nt < 4; ++nt) pacc[ct][nt] = (f32x4){0.f, 0.f, 0.f, 0.f};
#pragma unroll
    for (int ks = 0; ks < 4; ++ks) {
        bf16x8 wa[2], ab[4];
#pragma unroll
        for (int ct = 0; ct < 2; ++ct) {
            int co = wv * 32 + ct * 16 + lr;
            wa[ct] = *(const bf16x8*)(wprojT + co * 128 + ks * 32 + lg * 8);
        }
#pragma unroll
        for (int nt = 0; nt < 4; ++nt) {
            int n = nt * 16 + lr;
            ab[nt] = *(const bf16x8*)&s_x[(n * 128 + ks * 32 + lg * 8) ^ ((n & 15) << 3)];
        }
#pragma unroll
        for (int ct = 0; ct < 2; ++ct)
#pragma unroll
            for (int nt = 0; nt < 4; ++nt)
                pacc[ct][nt] = MFMA16(wa[ct], ab[nt], pacc[ct][nt]);
    }

    // ---- epilogue: residual + bias; pool partials; DIRECT register stores ----
    float bp[2][4];
#pragma unroll
    for (int ct = 0; ct < 2; ++ct)
#pragma unroll
        for (int r = 0; r < 4; ++r) bp[ct][r] = b_proj[wv * 32 + ct * 16 + lg * 4 + r];

    float ps[2][4], pm[2][4];
    if constexpr (STAGE == 1) {
#pragma unroll
        for (int ct = 0; ct < 2; ++ct)
#pragma unroll
            for (int r = 0; r < 4; ++r) { ps[ct][r] = 0.f; pm[ct][r] = -1e30f; }
    }

#pragma unroll
    for (int ct = 0; ct < 2; ++ct)
#pragma unroll
        for (int nt = 0; nt < 4; ++nt) {
            int n = nt * 16 + lr;
            int c0 = wv * 32 + ct * 16 + lg * 4;
            bf16x4 o;
#pragma unroll
            for (int r = 0; r < 4; ++r) {
                float v = (float)resr[ct][nt][r] + bp[ct][r] + pacc[ct][nt][r];
                o[r] = (bf16)v;
                if constexpr (STAGE == 1) {
                    ps[ct][r] += v;
                    pm[ct][r] = fmaxf(pm[ct][r], v);
                }
            }
            size_t pix;
            if constexpr (STAGE == 0) {
                int ph = wr * 8 + (n >> 3), pw = wc * 8 + (n & 7);
                int gw = ((ph & 31) << 5) + (pw & 31);
                int nn = ((ph >> 5) << 3) + (pw >> 5);
                pix = (size_t)b * 65536 + (size_t)gw * 64 + nn;
            } else {
                pix = (size_t)b * 65536 + (size_t)(wr * 32 + wc) * 64 + n;
            }
            *(bf16x4*)(xout + pix * 128 + c0) = o;
        }

    if constexpr (STAGE == 1) {
        const int w = blk & 1023;
        float* prow_s = psum + (size_t)w * 512 + b * 128;
        float* prow_m = pmax + (size_t)w * 512 + b * 128;
#pragma unroll
        for (int ct = 0; ct < 2; ++ct) {
            f32x4 sv, mv;
#pragma unroll
            for (int r = 0; r < 4; ++r) {
                float s = ps[ct][r], m = pm[ct][r];
#pragma unroll
                for (int o = 1; o < 16; o <<= 1) {
                    s += __shfl_xor(s, o);
                    m = fmaxf(m, __shfl_xor(m, o));
                }
                sv[r] = s; mv[r] = m;
            }
            if (lr == 0) {
                int cbase = wv * 32 + ct * 16 + lg * 4;
                *(f32x4*)&prow_s[cbase] = sv;     // 16B vector store (full lines)
                *(f32x4*)&prow_m[cbase] = mv;
            }
        }
    }
}

// ---- reduce pooling partials: avg/mx[b*128+c] over 1024 windows ----
__global__ __launch_bounds__(64) void reduce_kernel(const float* __restrict__ psum,
                                                    const float* __restrict__ pmax,
                                                    float* __restrict__ avg,
                                                    float* __restrict__ mx)
{
    int bc = blockIdx.x;        // 0..511
    int t = threadIdx.x;        // 0..63
    float s = 0.f, m = -1e30f;
#pragma unroll
    for (int k = 0; k < 16; ++k) {
        size_t w = t + k * 64;
        s += psum[w * 512 + bc];
        m = fmaxf(m, pmax[w * 512 + bc]);
    }
#pragma unroll
    for (int o = 1; o < 64; o <<= 1) {
        s += __shfl_xor(s, o);
        m = fmaxf(m, __shfl_xor(m, o));
    }
    if (t == 0) { avg[bc] = s * (1.f / 65536.f); mx[bc] = m; }
}

// ---- gate = sigmoid( (relu(avg@W1)+relu(mx@W1)) @ W2 ) ----
__global__ void gate_kernel(const float* __restrict__ avg, const float* __restrict__ mxp,
                            const float* __restrict__ w1, const float* __restrict__ w2,
                            float* __restrict__ gate)
{
    __shared__ float la[512], lm[512], s1[512];
    int t = threadIdx.x;
    la[t] = avg[t];
    lm[t] = mxp[t];
    __syncthreads();
    int b = t >> 7, co = t & 127;
    float a1 = 0.f, m1 = 0.f;
    for (int c = 0; c < 128; ++c) {
        float w = w1[c * 128 + co];
        a1 += la[b * 128 + c] * w;
        m1 += lm[b * 128 + c] * w;
    }
    s1[t] = fmaxf(a1, 0.f) + fmaxf(m1, 0.f);
    __syncthreads();
    float g = 0.f;
    for (int c = 0; c < 128; ++c) g += s1[b * 128 + c] * w2[c * 128 + co];
    gate[t] = 1.f / (1.f + __expf(-g));
}

// ---- k4: x2 (grid-major bf16) * gate -> out NCHW fp32 (tiled LDS transpose) ----
__global__ __launch_bounds__(256) void tout_kernel(const bf16* __restrict__ x2,
                                                   const float* __restrict__ gate,
                                                   float* __restrict__ out)
{
    __shared__ float s[128 * 68];
    __shared__ float sg[128];
    const int blk = blockIdx.x;            // b*1024 + chunk(64px within one row)
    const int b = blk >> 10;
    const int chunk = blk & 1023;
    const int ph = chunk >> 2, pw0 = (chunk & 3) * 64;
    const int gwb = (ph & 31) << 5;
    const int nb  = ((ph >> 5) << 3) + (pw0 >> 5);
    const int t = threadIdx.x;
    if (t < 128) sg[t] = gate[b * 128 + t];
    __syncthreads();
    const bf16* base = x2 + (size_t)b * 65536 * 128;
#pragma unroll
    for (int i = 0; i < 4; ++i) {
        int idx8 = t + i * 256;            // 0..1023 = 64px * 16 chunks
        int px = idx8 >> 4, c8 = idx8 & 15;
        size_t pi = (size_t)(gwb + (px & 31)) * 64 + nb + (px >> 5);
        bf16x8 v = *(const bf16x8*)(base + pi * 128 + c8 * 8);
        int pxs = px ^ ((c8 & 7) << 3);
#pragma unroll
        for (int j = 0; j < 8; ++j) {
            int c = c8 * 8 + j;
            s[c * 68 + pxs] = (float)v[j] * sg[c];
        }
    }
    __syncthreads();
    int cg = t >> 4, pl = (t & 15) * 4;
#pragma unroll
    for (int i = 0; i < 8; ++i) {
        int c = cg + i * 16;
        int pp = pl ^ (((c >> 3) & 7) << 3);
        f32x4 w = *(const f32x4*)&s[c * 68 + pp];
        *(f32x4*)&out[((size_t)(b * 128 + c)) * 65536 + ph * 256 + pw0 + pl] = w;
    }
}

extern "C" void kernel_launch(void* const* d_in, const int* in_sizes, int n_in,
                              void* d_out, int out_size, void* d_ws, size_t ws_size,
                              hipStream_t stream)
{
    const float* x      = (const float*)d_in[0];
    const float* w_qkv  = (const float*)d_in[1];
    const float* b_qkv  = (const float*)d_in[2];
    const float* w_proj = (const float*)d_in[3];
    const float* b_proj = (const float*)d_in[4];
    const float* rpb    = (const float*)d_in[5];
    const float* cf_w1  = (const float*)d_in[6];
    const float* cf_w2  = (const float*)d_in[7];
    float* out = (float*)d_out;

    char* ws = (char*)d_ws;
    // ws[0:64MB] = xT (bf16 linear NHWC, dead after attn<0>)
    //            = x2 (bf16 grid-major, written by attn<1>, read by tout)
    bf16* xT = (bf16*)ws;
    bf16* x2 = (bf16*)ws;
    char* tail = ws + 67108864;                      // 64 MB
    bf16*  wqkvT  = (bf16*)tail;                     // 96 KB
    bf16*  wprojT = (bf16*)(tail + 98304);           // 32 KB
    float* psum   = (float*)(tail + 131072);         // 2 MB  (1024 windows x 512)
    float* pmax   = (float*)(tail + 131072 + 2097152);   // 2 MB
    float* avg    = (float*)(tail + 131072 + 4194304);   // 2 KB
    float* mxp    = (float*)(tail + 131072 + 4196352);   // 2 KB
    float* gate   = (float*)(tail + 131072 + 4198400);   // 2 KB
    bf16*  biasC  = (bf16*)(tail + 131072 + 4200448);    // 32 KB
    bf16*  x1T    = (bf16*)d_out;                    // grid-major bf16, 64MB, dead after attn<1>

    tin_kernel<<<4096, 256, 0, stream>>>(x, xT);
    wconv_kernel<<<256, 256, 0, stream>>>(w_qkv, w_proj, rpb, wqkvT, wprojT, biasC);
    attn_kernel<0><<<4096, 256, 0, stream>>>(xT,  x1T, wqkvT, wprojT,
                                             b_qkv, b_proj, biasC, nullptr, nullptr);
    attn_kernel<1><<<4096, 256, 0, stream>>>(x1T, x2,  wqkvT, wprojT,
                                             b_qkv, b_proj, biasC, psum, pmax);
    reduce_kernel<<<512, 64, 0, stream>>>(psum, pmax, avg, mxp);
    gate_kernel<<<1, 512, 0, stream>>>(avg, mxp, cf_w1, cf_w2, gate);
    tout_kernel<<<4096, 256, 0, stream>>>(x2, gate, out);
}

// Round 18
// 345.047 us; speedup vs baseline: 1.3751x; 1.3751x over previous
//
#include <hip/hip_runtime.h>
#include <hip/hip_bf16.h>
#include <stdint.h>

typedef __bf16 bf16;
typedef bf16 bf16x8 __attribute__((ext_vector_type(8)));
typedef bf16 bf16x4 __attribute__((ext_vector_type(4)));
typedef float f32x4 __attribute__((ext_vector_type(4)));

#define MFMA16(a, b, c) __builtin_amdgcn_mfma_f32_16x16x32_bf16((a), (b), (c), 0, 0, 0)
#define QKSWZ(n) ((((n) >> 2) & 3) << 3)
#define LGKM0() do { asm volatile("s_waitcnt lgkmcnt(0)" ::: "memory"); \
                     __builtin_amdgcn_sched_barrier(0); } while (0)

// ---- k0: x [B,C,H,W] fp32 -> xT [B,H,W,C] bf16 linear (tiled LDS transpose) ----
__global__ __launch_bounds__(256) void tin_kernel(const float* __restrict__ x,
                                                  bf16* __restrict__ xT)
{
    __shared__ float s[128 * 65];
    const int blk = blockIdx.x;            // b*1024 + pxchunk
    const int b = blk >> 10;
    const int px0 = (blk & 1023) * 64;
    const int tid = threadIdx.x;
    {
        int c0 = tid >> 6, pxl = tid & 63;
        const float* src = x + (size_t)b * 8388608 + px0 + pxl;
#pragma unroll
        for (int i = 0; i < 32; ++i) {
            int c = c0 + i * 4;
            s[c * 65 + pxl] = src[(size_t)c * 65536];
        }
    }
    __syncthreads();
    int px = tid >> 2, piece = tid & 3;
    bf16* dstp = xT + ((size_t)b * 65536 + px0 + px) * 128;
#pragma unroll
    for (int k = 0; k < 4; ++k) {
        bf16x8 v8;
        int cb = (k * 4 + piece) * 8;
#pragma unroll
        for (int j = 0; j < 8; ++j) v8[j] = (bf16)s[(cb + j) * 65 + px];
        *(bf16x8*)(dstp + cb) = v8;
    }
}

// ---- convert+transpose weights to bf16 + precompute per-lane bias fragments ----
// biasC[h*4096 + i*512 + lane*8 + s]: bias for softmax element e=i*8+s of lane,
// head h, in the sacc fragment order (e = (mt*4+nt)*4+r). Same for all windows.
__global__ void wconv_kernel(const float* __restrict__ w_qkv,
                             const float* __restrict__ w_proj,
                             const float* __restrict__ rpb,
                             bf16* __restrict__ wqkvT,
                             bf16* __restrict__ wprojT,
                             bf16* __restrict__ biasC)
{
    int id = blockIdx.x * 256 + threadIdx.x;
    if (id < 16384) {
        int s = id & 7, lane = (id >> 3) & 63, i = (id >> 9) & 7, h = id >> 12;
        int e = i * 8 + s;
        int mt = e >> 4, nt = (e >> 2) & 3, r = e & 3;
        int n = nt * 16 + (lane & 15);
        int m = mt * 16 + (lane >> 4) * 4 + r;
        int rel = ((n >> 3) - (m >> 3) + 7) * 15 + ((n & 7) - (m & 7) + 7);
        biasC[id] = (bf16)rpb[rel * 4 + h];
    }
    if (id < 49152) {                       // 384*128
        int co = id >> 7, c = id & 127;
        wqkvT[id] = (bf16)w_qkv[c * 384 + co];
    } else {
        int id2 = id - 49152;               // 128*128
        int co = id2 >> 7, c = id2 & 127;
        wprojT[id2] = (bf16)w_proj[c * 128 + co];
    }
}

// ---- fused window/grid relative attention, one 8x8 window per block ----
// Own-head decomposition, 3-pass QKV (q,k,v; 2 tiles each, immediate flush).
// Per-wave 4KB exchange quarters (q->k->P halves in s_ex; vT in s_x quarter).
// 4 block barriers; direct-register epilogue; precomputed bias fragments.
// LDS 32KB, launch_bounds(256,4): 4 blocks/CU = 128KB LDS, VGPR cap 128 (>84,
// no spill; (256,5) clamps to 48 and spills massively -- R17 lesson).
// NOTE (R15 lesson): multi-window sequential loops per block regress badly.
// STAGE 0: window partition; in = xT linear, out = x1T grid-major (scatter)
// STAGE 1: grid partition; in/out grid-major CONTIG 16KB + pooling partials
template<int STAGE>
__global__ __launch_bounds__(256, 4)
void attn_kernel(const bf16* __restrict__ xin, bf16* __restrict__ xout,
                 const bf16* __restrict__ wqkvT, const bf16* __restrict__ wprojT,
                 const float* __restrict__ b_qkv, const float* __restrict__ b_proj,
                 const bf16* __restrict__ biasC,
                 float* __restrict__ psum, float* __restrict__ pmax)
{
    __shared__ __align__(16) bf16 s_x[8192];   // input [n][c] -> vT quarters -> attnout
    __shared__ __align__(16) bf16 s_ex[8192];  // per-wave 4KB: q -> k -> P halves

    const int tid = threadIdx.x;
    const int lane = tid & 63;
    const int wv = tid >> 6;     // wave = head
    const int lr = lane & 15;
    const int lg = lane >> 4;
    bf16* exq = s_ex + wv * 2048;              // per-wave exchange quarter
    bf16* exv = s_x + wv * 2048;               // per-wave vT quarter (valid after B2)

    const int blk = (blockIdx.x & 7) * 512 + (blockIdx.x >> 3);  // XCD-bijective
    const int b  = blk >> 10;
    const int wr = (blk >> 5) & 31;
    const int wc = blk & 31;

    // ---- stage input window into LDS ----
    if constexpr (STAGE == 0) {
        int n = tid >> 2, piece = tid & 3;
        int ph = wr * 8 + (n >> 3), pw = wc * 8 + (n & 7);
        const bf16* src = xin + ((size_t)b * 65536 + (size_t)ph * 256 + pw) * 128;
#pragma unroll
        for (int k = 0; k < 4; ++k) {
            int cc = (k * 4 + piece) * 8;
            bf16x8 v = *(const bf16x8*)(src + cc);
            *(bf16x8*)&s_x[(n * 128 + cc) ^ ((n & 15) << 3)] = v;
        }
    } else {
        const bf16* src = xin + ((size_t)b * 65536 + (size_t)(wr * 32 + wc) * 64) * 128;
#pragma unroll
        for (int k = 0; k < 4; ++k) {
            int g = k * 256 + tid;
            int n = g >> 4, cc = (g & 15) * 8;
            bf16x8 v = *(const bf16x8*)(src + g * 8);
            *(bf16x8*)&s_x[(n * 128 + cc) ^ ((n & 15) << 3)] = v;
        }
    }

    __syncthreads();   // B1

    // ---- pass Q: 2 tiles, scatter to exq, fragments to regs ----
    bf16x8 qb[4];
    {
        f32x4 acc[4][2];
#pragma unroll
        for (int mt = 0; mt < 4; ++mt)
#pragma unroll
            for (int t = 0; t < 2; ++t) acc[mt][t] = (f32x4){0.f, 0.f, 0.f, 0.f};
        bf16x8 wB[2][4];
#pragma unroll
        for (int t = 0; t < 2; ++t) {
            int co = wv * 32 + t * 16 + lr;
            const bf16* rp = wqkvT + co * 128 + lg * 8;
#pragma unroll
            for (int ks = 0; ks < 4; ++ks) wB[t][ks] = *(const bf16x8*)(rp + ks * 32);
        }
#pragma unroll
        for (int ks = 0; ks < 4; ++ks) {
            bf16x8 a[4];
#pragma unroll
            for (int mt = 0; mt < 4; ++mt) {
                int n = mt * 16 + lr;
                a[mt] = *(const bf16x8*)&s_x[(n * 128 + ks * 32 + lg * 8) ^ ((n & 15) << 3)];
            }
#pragma unroll
            for (int mt = 0; mt < 4; ++mt)
#pragma unroll
                for (int t = 0; t < 2; ++t)
                    acc[mt][t] = MFMA16(a[mt], wB[t][ks], acc[mt][t]);
        }
#pragma unroll
        for (int t = 0; t < 2; ++t) {
            float bias = b_qkv[wv * 32 + t * 16 + lr];
            int d = t * 16 + lr;
#pragma unroll
            for (int mt = 0; mt < 4; ++mt) {
                int n0 = mt * 16 + lg * 4;
#pragma unroll
                for (int r = 0; r < 4; ++r) {
                    int n = n0 + r;
                    exq[n * 32 + (d ^ QKSWZ(n))] = (bf16)(acc[mt][t][r] + bias);
                }
            }
        }
        LGKM0();
#pragma unroll
        for (int t = 0; t < 4; ++t) {
            int m = t * 16 + lr;
            qb[t] = *(const bf16x8*)&exq[m * 32 + ((lg * 8) ^ QKSWZ(m))];
        }
        LGKM0();   // qb landed before k overwrites quarter
    }

    // ---- pass K: 2 tiles, scatter to exq ----
    {
        f32x4 acc[4][2];
#pragma unroll
        for (int mt = 0; mt < 4; ++mt)
#pragma unroll
            for (int t = 0; t < 2; ++t) acc[mt][t] = (f32x4){0.f, 0.f, 0.f, 0.f};
        bf16x8 wB[2][4];
#pragma unroll
        for (int t = 0; t < 2; ++t) {
            int co = 128 + wv * 32 + t * 16 + lr;
            const bf16* rp = wqkvT + co * 128 + lg * 8;
#pragma unroll
            for (int ks = 0; ks < 4; ++ks) wB[t][ks] = *(const bf16x8*)(rp + ks * 32);
        }
#pragma unroll
        for (int ks = 0; ks < 4; ++ks) {
            bf16x8 a[4];
#pragma unroll
            for (int mt = 0; mt < 4; ++mt) {
                int n = mt * 16 + lr;
                a[mt] = *(const bf16x8*)&s_x[(n * 128 + ks * 32 + lg * 8) ^ ((n & 15) << 3)];
            }
#pragma unroll
            for (int mt = 0; mt < 4; ++mt)
#pragma unroll
                for (int t = 0; t < 2; ++t)
                    acc[mt][t] = MFMA16(a[mt], wB[t][ks], acc[mt][t]);
        }
#pragma unroll
        for (int t = 0; t < 2; ++t) {
            float bias = b_qkv[128 + wv * 32 + t * 16 + lr];
            int d = t * 16 + lr;
#pragma unroll
            for (int mt = 0; mt < 4; ++mt) {
                int n0 = mt * 16 + lg * 4;
#pragma unroll
                for (int r = 0; r < 4; ++r) {
                    int n = n0 + r;
                    exq[n * 32 + (d ^ QKSWZ(n))] = (bf16)(acc[mt][t][r] + bias);
                }
            }
        }
    }

    // residual -> registers (before s_x quarters get overwritten by vT)
    bf16x4 resr[2][4];
#pragma unroll
    for (int ct = 0; ct < 2; ++ct)
#pragma unroll
        for (int nt = 0; nt < 4; ++nt) {
            int n = nt * 16 + lr;
            int c0 = wv * 32 + ct * 16 + lg * 4;
            resr[ct][nt] = *(const bf16x4*)&s_x[(n * 128 + c0) ^ ((n & 15) << 3)];
        }

    // ---- pass V: 2 tiles (held briefly), flush to s_x quarter after B2 ----
    f32x4 accV[4][2];
    {
#pragma unroll
        for (int mt = 0; mt < 4; ++mt)
#pragma unroll
            for (int t = 0; t < 2; ++t) accV[mt][t] = (f32x4){0.f, 0.f, 0.f, 0.f};
        bf16x8 wB[2][4];
#pragma unroll
        for (int t = 0; t < 2; ++t) {
            int co = 256 + wv * 32 + t * 16 + lr;
            const bf16* rp = wqkvT + co * 128 + lg * 8;
#pragma unroll
            for (int ks = 0; ks < 4; ++ks) wB[t][ks] = *(const bf16x8*)(rp + ks * 32);
        }
#pragma unroll
        for (int ks = 0; ks < 4; ++ks) {
            bf16x8 a[4];
#pragma unroll
            for (int mt = 0; mt < 4; ++mt) {
                int n = mt * 16 + lr;
                a[mt] = *(const bf16x8*)&s_x[(n * 128 + ks * 32 + lg * 8) ^ ((n & 15) << 3)];
            }
#pragma unroll
            for (int mt = 0; mt < 4; ++mt)
#pragma unroll
                for (int t = 0; t < 2; ++t)
                    accV[mt][t] = MFMA16(a[mt], wB[t][ks], accV[mt][t]);
        }
    }

    // bias fragments -> registers (coalesced 16B loads, L1-hot; overlap w/ MFMA)
    bf16x8 bi[8];
    {
        const bf16* bpp = biasC + wv * 4096 + lane * 8;
#pragma unroll
        for (int i = 0; i < 8; ++i)
            bi[i] = *(const bf16x8*)(bpp + i * 512);
    }

    __syncthreads();   // B2: all s_x GEMM/residual reads done; quarters free

    // vT scatter -> own s_x quarter [d][64] swz (frees accV before softmax)
#pragma unroll
    for (int t = 0; t < 2; ++t) {
        float bias = b_qkv[256 + wv * 32 + t * 16 + lr];
        int d = t * 16 + lr;
#pragma unroll
        for (int mt = 0; mt < 4; ++mt) {
            bf16x4 v4;
#pragma unroll
            for (int r = 0; r < 4; ++r) v4[r] = (bf16)(accV[mt][t][r] + bias);
            int idx = (d * 64 + mt * 16 + lg * 4) ^ ((d & 7) << 3);
            *(bf16x4*)&exv[idx] = v4;
        }
    }

    // ---- S^T = K * Q^T (wave-local) ----
    f32x4 sacc[4][4];
#pragma unroll
    for (int mt = 0; mt < 4; ++mt)
#pragma unroll
        for (int nt = 0; nt < 4; ++nt) sacc[mt][nt] = (f32x4){0.f, 0.f, 0.f, 0.f};
#pragma unroll
    for (int mt = 0; mt < 4; ++mt) {
        int m = mt * 16 + lr;
        bf16x8 ka = *(const bf16x8*)&exq[m * 32 + ((lg * 8) ^ QKSWZ(m))];
#pragma unroll
        for (int nt = 0; nt < 4; ++nt)
            sacc[mt][nt] = MFMA16(ka, qb[nt], sacc[mt][nt]);
    }

    // softmax over m (scale 0.5 + precomputed bias fragment, pure FMA)
    float inv[4];
#pragma unroll
    for (int nt = 0; nt < 4; ++nt) {
        float mx = -1e30f;
#pragma unroll
        for (int mt = 0; mt < 4; ++mt)
#pragma unroll
            for (int r = 0; r < 4; ++r) {
                int e = (mt * 4 + nt) * 4 + r;
                float lgt = sacc[mt][nt][r] * 0.5f + (float)bi[e >> 3][e & 7];
                sacc[mt][nt][r] = lgt;
                mx = fmaxf(mx, lgt);
            }
        mx = fmaxf(mx, __shfl_xor(mx, 16));
        mx = fmaxf(mx, __shfl_xor(mx, 32));
        float sum = 0.f;
#pragma unroll
        for (int mt = 0; mt < 4; ++mt)
#pragma unroll
            for (int r = 0; r < 4; ++r) {
                float p = __expf(sacc[mt][nt][r] - mx);
                sacc[mt][nt][r] = p;
                sum += p;
            }
        sum += __shfl_xor(sum, 16);
        sum += __shfl_xor(sum, 32);
        inv[nt] = 1.f / sum;
    }
    LGKM0();   // ka reads + vT stores landed

    // v fragments -> registers
    bf16x8 va[2][2];
#pragma unroll
    for (int dt = 0; dt < 2; ++dt) {
        int d = dt * 16 + lr;
#pragma unroll
        for (int ks = 0; ks < 2; ++ks)
            va[dt][ks] = *(const bf16x8*)&exv[(d * 64 + ks * 32 + lg * 8) ^ ((d & 7) << 3)];
    }

    __syncthreads();   // B3: all waves' va preloads done -> s_x fully dead

    // ---- PV via P halves through exq: out^T[d][n] ----
    f32x4 oacc[2][4];
#pragma unroll
    for (int dt = 0; dt < 2; ++dt)
#pragma unroll
        for (int nt = 0; nt < 4; ++nt) oacc[dt][nt] = (f32x4){0.f, 0.f, 0.f, 0.f};
#pragma unroll
    for (int ks = 0; ks < 2; ++ks) {
#pragma unroll
        for (int nt = 0; nt < 4; ++nt) {
            int n = nt * 16 + lr;
#pragma unroll
            for (int mh = 0; mh < 2; ++mh) {
                int mt = ks * 2 + mh;
                bf16x4 v4;
#pragma unroll
                for (int r = 0; r < 4; ++r) v4[r] = (bf16)(sacc[mt][nt][r] * inv[nt]);
                int off = (mh * 16 + lg * 4) ^ ((n & 3) << 3);
                *(bf16x4*)&exq[n * 32 + off] = v4;
            }
        }
        LGKM0();
        bf16x8 pb[4];
#pragma unroll
        for (int nt = 0; nt < 4; ++nt) {
            int n = nt * 16 + lr;
            pb[nt] = *(const bf16x8*)&exq[n * 32 + ((lg * 8) ^ ((n & 3) << 3))];
        }
#pragma unroll
        for (int dt = 0; dt < 2; ++dt)
#pragma unroll
            for (int nt = 0; nt < 4; ++nt)
                oacc[dt][nt] = MFMA16(va[dt][ks], pb[nt], oacc[dt][nt]);
        LGKM0();   // pb reads landed before next half overwrites
    }

    // attn output -> s_x as [n][c] (safe: B3 passed; exq is wave-local)
#pragma unroll
    for (int dt = 0; dt < 2; ++dt)
#pragma unroll
        for (int nt = 0; nt < 4; ++nt) {
            int n = nt * 16 + lr;
            int c0 = wv * 32 + dt * 16 + lg * 4;
            bf16x4 v4;
#pragma unroll
            for (int r = 0; r < 4; ++r) v4[r] = (bf16)oacc[dt][nt][r];
            int idx = (n * 128 + c0) ^ ((n & 15) << 3);
            *(bf16x4*)&s_x[idx] = v4;
        }

    __syncthreads();   // B4: attnout complete

    // ---- proj: x1^T[co][n] = sum_c wproj[c][co] * attn[n][c] ----
    f32x4 pacc[2][4];
#pragma unroll
    for (int ct = 0; ct < 2; ++ct)
#pragma unroll
        for (int nt = 0; nt < 4; ++nt) pacc[ct][nt] = (f32x4){0.f, 0.f, 0.f, 0.f};
#pragma unroll
    for (int ks = 0; ks < 4; ++ks) {
        bf16x8 wa[2], ab[4];
#pragma unroll
        for (int ct = 0; ct < 2; ++ct) {
            int co = wv * 32 + ct * 16 + lr;
            wa[ct] = *(const bf16x8*)(wprojT + co * 128 + ks * 32 + lg * 8);
        }
#pragma unroll
        for (int nt = 0; nt < 4; ++nt) {
            int n = nt * 16 + lr;
            ab[nt] = *(const bf16x8*)&s_x[(n * 128 + ks * 32 + lg * 8) ^ ((n & 15) << 3)];
        }
#pragma unroll
        for (int ct = 0; ct < 2; ++ct)
#pragma unroll
            for (int nt = 0; nt < 4; ++nt)
                pacc[ct][nt] = MFMA16(wa[ct], ab[nt], pacc[ct][nt]);
    }

    // ---- epilogue: residual + bias; pool partials; DIRECT register stores ----
    float bp[2][4];
#pragma unroll
    for (int ct = 0; ct < 2; ++ct)
#pragma unroll
        for (int r = 0; r < 4; ++r) bp[ct][r] = b_proj[wv * 32 + ct * 16 + lg * 4 + r];

    float ps[2][4], pm[2][4];
    if constexpr (STAGE == 1) {
#pragma unroll
        for (int ct = 0; ct < 2; ++ct)
#pragma unroll
            for (int r = 0; r < 4; ++r) { ps[ct][r] = 0.f; pm[ct][r] = -1e30f; }
    }

#pragma unroll
    for (int ct = 0; ct < 2; ++ct)
#pragma unroll
        for (int nt = 0; nt < 4; ++nt) {
            int n = nt * 16 + lr;
            int c0 = wv * 32 + ct * 16 + lg * 4;
            bf16x4 o;
#pragma unroll
            for (int r = 0; r < 4; ++r) {
                float v = (float)resr[ct][nt][r] + bp[ct][r] + pacc[ct][nt][r];
                o[r] = (bf16)v;
                if constexpr (STAGE == 1) {
                    ps[ct][r] += v;
                    pm[ct][r] = fmaxf(pm[ct][r], v);
                }
            }
            size_t pix;
            if constexpr (STAGE == 0) {
                int ph = wr * 8 + (n >> 3), pw = wc * 8 + (n & 7);
                int gw = ((ph & 31) << 5) + (pw & 31);
                int nn = ((ph >> 5) << 3) + (pw >> 5);
                pix = (size_t)b * 65536 + (size_t)gw * 64 + nn;
            } else {
                pix = (size_t)b * 65536 + (size_t)(wr * 32 + wc) * 64 + n;
            }
            *(bf16x4*)(xout + pix * 128 + c0) = o;
        }

    if constexpr (STAGE == 1) {
        const int w = blk & 1023;
        float* prow_s = psum + (size_t)w * 512 + b * 128;
        float* prow_m = pmax + (size_t)w * 512 + b * 128;
#pragma unroll
        for (int ct = 0; ct < 2; ++ct) {
            f32x4 sv, mv;
#pragma unroll
            for (int r = 0; r < 4; ++r) {
                float s = ps[ct][r], m = pm[ct][r];
#pragma unroll
                for (int o = 1; o < 16; o <<= 1) {
                    s += __shfl_xor(s, o);
                    m = fmaxf(m, __shfl_xor(m, o));
                }
                sv[r] = s; mv[r] = m;
            }
            if (lr == 0) {
                int cbase = wv * 32 + ct * 16 + lg * 4;
                *(f32x4*)&prow_s[cbase] = sv;     // 16B vector store (full lines)
                *(f32x4*)&prow_m[cbase] = mv;
            }
        }
    }
}

// ---- reduce pooling partials: avg/mx[b*128+c] over 1024 windows ----
__global__ __launch_bounds__(64) void reduce_kernel(const float* __restrict__ psum,
                                                    const float* __restrict__ pmax,
                                                    float* __restrict__ avg,
                                                    float* __restrict__ mx)
{
    int bc = blockIdx.x;        // 0..511
    int t = threadIdx.x;        // 0..63
    float s = 0.f, m = -1e30f;
#pragma unroll
    for (int k = 0; k < 16; ++k) {
        size_t w = t + k * 64;
        s += psum[w * 512 + bc];
        m = fmaxf(m, pmax[w * 512 + bc]);
    }
#pragma unroll
    for (int o = 1; o < 64; o <<= 1) {
        s += __shfl_xor(s, o);
        m = fmaxf(m, __shfl_xor(m, o));
    }
    if (t == 0) { avg[bc] = s * (1.f / 65536.f); mx[bc] = m; }
}

// ---- gate = sigmoid( (relu(avg@W1)+relu(mx@W1)) @ W2 ) ----
__global__ void gate_kernel(const float* __restrict__ avg, const float* __restrict__ mxp,
                            const float* __restrict__ w1, const float* __restrict__ w2,
                            float* __restrict__ gate)
{
    __shared__ float la[512], lm[512], s1[512];
    int t = threadIdx.x;
    la[t] = avg[t];
    lm[t] = mxp[t];
    __syncthreads();
    int b = t >> 7, co = t & 127;
    float a1 = 0.f, m1 = 0.f;
    for (int c = 0; c < 128; ++c) {
        float w = w1[c * 128 + co];
        a1 += la[b * 128 + c] * w;
        m1 += lm[b * 128 + c] * w;
    }
    s1[t] = fmaxf(a1, 0.f) + fmaxf(m1, 0.f);
    __syncthreads();
    float g = 0.f;
    for (int c = 0; c < 128; ++c) g += s1[b * 128 + c] * w2[c * 128 + co];
    gate[t] = 1.f / (1.f + __expf(-g));
}

// ---- k4: x2 (grid-major bf16) * gate -> out NCHW fp32 (tiled LDS transpose) ----
__global__ __launch_bounds__(256) void tout_kernel(const bf16* __restrict__ x2,
                                                   const float* __restrict__ gate,
                                                   float* __restrict__ out)
{
    __shared__ float s[128 * 68];
    __shared__ float sg[128];
    const int blk = blockIdx.x;            // b*1024 + chunk(64px within one row)
    const int b = blk >> 10;
    const int chunk = blk & 1023;
    const int ph = chunk >> 2, pw0 = (chunk & 3) * 64;
    const int gwb = (ph & 31) << 5;
    const int nb  = ((ph >> 5) << 3) + (pw0 >> 5);
    const int t = threadIdx.x;
    if (t < 128) sg[t] = gate[b * 128 + t];
    __syncthreads();
    const bf16* base = x2 + (size_t)b * 65536 * 128;
#pragma unroll
    for (int i = 0; i < 4; ++i) {
        int idx8 = t + i * 256;            // 0..1023 = 64px * 16 chunks
        int px = idx8 >> 4, c8 = idx8 & 15;
        size_t pi = (size_t)(gwb + (px & 31)) * 64 + nb + (px >> 5);
        bf16x8 v = *(const bf16x8*)(base + pi * 128 + c8 * 8);
        int pxs = px ^ ((c8 & 7) << 3);
#pragma unroll
        for (int j = 0; j < 8; ++j) {
            int c = c8 * 8 + j;
            s[c * 68 + pxs] = (float)v[j] * sg[c];
        }
    }
    __syncthreads();
    int cg = t >> 4, pl = (t & 15) * 4;
#pragma unroll
    for (int i = 0; i < 8; ++i) {
        int c = cg + i * 16;
        int pp = pl ^ (((c >> 3) & 7) << 3);
        f32x4 w = *(const f32x4*)&s[c * 68 + pp];
        *(f32x4*)&out[((size_t)(b * 128 + c)) * 65536 + ph * 256 + pw0 + pl] = w;
    }
}

extern "C" void kernel_launch(void* const* d_in, const int* in_sizes, int n_in,
                              void* d_out, int out_size, void* d_ws, size_t ws_size,
                              hipStream_t stream)
{
    const float* x      = (const float*)d_in[0];
    const float* w_qkv  = (const float*)d_in[1];
    const float* b_qkv  = (const float*)d_in[2];
    const float* w_proj = (const float*)d_in[3];
    const float* b_proj = (const float*)d_in[4];
    const float* rpb    = (const float*)d_in[5];
    const float* cf_w1  = (const float*)d_in[6];
    const float* cf_w2  = (const float*)d_in[7];
    float* out = (float*)d_out;

    char* ws = (char*)d_ws;
    // ws[0:64MB] = xT (bf16 linear NHWC, dead after attn<0>)
    //            = x2 (bf16 grid-major, written by attn<1>, read by tout)
    bf16* xT = (bf16*)ws;
    bf16* x2 = (bf16*)ws;
    char* tail = ws + 67108864;                      // 64 MB
    bf16*  wqkvT  = (bf16*)tail;                     // 96 KB
    bf16*  wprojT = (bf16*)(tail + 98304);           // 32 KB
    float* psum   = (float*)(tail + 131072);         // 2 MB  (1024 windows x 512)
    float* pmax   = (float*)(tail + 131072 + 2097152);   // 2 MB
    float* avg    = (float*)(tail + 131072 + 4194304);   // 2 KB
    float* mxp    = (float*)(tail + 131072 + 4196352);   // 2 KB
    float* gate   = (float*)(tail + 131072 + 4198400);   // 2 KB
    bf16*  biasC  = (bf16*)(tail + 131072 + 4200448);    // 32 KB
    bf16*  x1T    = (bf16*)d_out;                    // grid-major bf16, 64MB, dead after attn<1>

    tin_kernel<<<4096, 256, 0, stream>>>(x, xT);
    wconv_kernel<<<256, 256, 0, stream>>>(w_qkv, w_proj, rpb, wqkvT, wprojT, biasC);
    attn_kernel<0><<<4096, 256, 0, stream>>>(xT,  x1T, wqkvT, wprojT,
                                             b_qkv, b_proj, biasC, nullptr, nullptr);
    attn_kernel<1><<<4096, 256, 0, stream>>>(x1T, x2,  wqkvT, wprojT,
                                             b_qkv, b_proj, biasC, psum, pmax);
    reduce_kernel<<<512, 64, 0, stream>>>(psum, pmax, avg, mxp);
    gate_kernel<<<1, 512, 0, stream>>>(avg, mxp, cf_w1, cf_w2, gate);
    tout_kernel<<<4096, 256, 0, stream>>>(x2, gate, out);
}

// Round 19
// 290.362 us; speedup vs baseline: 1.6340x; 1.1883x over previous
//
#include <hip/hip_runtime.h>
#include <hip/hip_bf16.h>
#include <stdint.h>

typedef __bf16 bf16;
typedef bf16 bf16x8 __attribute__((ext_vector_type(8)));
typedef bf16 bf16x4 __attribute__((ext_vector_type(4)));
typedef float f32x4 __attribute__((ext_vector_type(4)));

#define MFMA16(a, b, c) __builtin_amdgcn_mfma_f32_16x16x32_bf16((a), (b), (c), 0, 0, 0)
#define QKSWZ(n) ((((n) >> 2) & 3) << 3)
#define LGKM0() do { asm volatile("s_waitcnt lgkmcnt(0)" ::: "memory"); \
                     __builtin_amdgcn_sched_barrier(0); } while (0)

// ---- k0: x [B,C,H,W] fp32 -> xT [B,H,W,C] bf16 linear (tiled LDS transpose) ----
__global__ __launch_bounds__(256) void tin_kernel(const float* __restrict__ x,
                                                  bf16* __restrict__ xT)
{
    __shared__ float s[128 * 65];
    const int blk = blockIdx.x;            // b*1024 + pxchunk
    const int b = blk >> 10;
    const int px0 = (blk & 1023) * 64;
    const int tid = threadIdx.x;
    {
        int c0 = tid >> 6, pxl = tid & 63;
        const float* src = x + (size_t)b * 8388608 + px0 + pxl;
#pragma unroll
        for (int i = 0; i < 32; ++i) {
            int c = c0 + i * 4;
            s[c * 65 + pxl] = src[(size_t)c * 65536];
        }
    }
    __syncthreads();
    int px = tid >> 2, piece = tid & 3;
    bf16* dstp = xT + ((size_t)b * 65536 + px0 + px) * 128;
#pragma unroll
    for (int k = 0; k < 4; ++k) {
        bf16x8 v8;
        int cb = (k * 4 + piece) * 8;
#pragma unroll
        for (int j = 0; j < 8; ++j) v8[j] = (bf16)s[(cb + j) * 65 + px];
        *(bf16x8*)(dstp + cb) = v8;
    }
}

// ---- convert+transpose weights to bf16 + precompute per-lane bias fragments ----
// biasC[h*4096 + i*512 + lane*8 + s]: bias for softmax element e=i*8+s of lane,
// head h, in the sacc fragment order (e = (mt*4+nt)*4+r). Same for all windows.
__global__ void wconv_kernel(const float* __restrict__ w_qkv,
                             const float* __restrict__ w_proj,
                             const float* __restrict__ rpb,
                             bf16* __restrict__ wqkvT,
                             bf16* __restrict__ wprojT,
                             bf16* __restrict__ biasC)
{
    int id = blockIdx.x * 256 + threadIdx.x;
    if (id < 16384) {
        int s = id & 7, lane = (id >> 3) & 63, i = (id >> 9) & 7, h = id >> 12;
        int e = i * 8 + s;
        int mt = e >> 4, nt = (e >> 2) & 3, r = e & 3;
        int n = nt * 16 + (lane & 15);
        int m = mt * 16 + (lane >> 4) * 4 + r;
        int rel = ((n >> 3) - (m >> 3) + 7) * 15 + ((n & 7) - (m & 7) + 7);
        biasC[id] = (bf16)rpb[rel * 4 + h];
    }
    if (id < 49152) {                       // 384*128
        int co = id >> 7, c = id & 127;
        wqkvT[id] = (bf16)w_qkv[c * 384 + co];
    } else {
        int id2 = id - 49152;               // 128*128
        int co = id2 >> 7, c = id2 & 127;
        wprojT[id2] = (bf16)w_proj[c * 128 + co];
    }
}

// ---- fused window/grid relative attention, one 8x8 window per block ----
// Own-head decomposition, 3-pass QKV (q,k,v; 2 tiles each, immediate flush).
// Per-wave 4KB exchange quarters (q->k->P halves in s_ex; vT in s_x quarter).
// 4 block barriers; direct-register epilogue; precomputed bias fragments.
// LDS 32KB, launch_bounds(256,3): VGPR=84 (128-granule), zero spill.
// R17/R18 lesson: (256,4)/(256,5) clamp VGPR to 64/48 and spill massively;
// the 64-reg granule makes >3 waves/SIMD unreachable without spills.
// R15 lesson: multi-window sequential loops per block regress badly.
// STAGE 0: window partition; in = xT linear, out = x1T grid-major (scatter)
// STAGE 1: grid partition; in/out grid-major CONTIG 16KB + pooling partials
template<int STAGE>
__global__ __launch_bounds__(256, 3)
void attn_kernel(const bf16* __restrict__ xin, bf16* __restrict__ xout,
                 const bf16* __restrict__ wqkvT, const bf16* __restrict__ wprojT,
                 const float* __restrict__ b_qkv, const float* __restrict__ b_proj,
                 const bf16* __restrict__ biasC,
                 float* __restrict__ psum, float* __restrict__ pmax)
{
    __shared__ __align__(16) bf16 s_x[8192];   // input [n][c] -> vT quarters -> attnout
    __shared__ __align__(16) bf16 s_ex[8192];  // per-wave 4KB: q -> k -> P halves

    const int tid = threadIdx.x;
    const int lane = tid & 63;
    const int wv = tid >> 6;     // wave = head
    const int lr = lane & 15;
    const int lg = lane >> 4;
    bf16* exq = s_ex + wv * 2048;              // per-wave exchange quarter
    bf16* exv = s_x + wv * 2048;               // per-wave vT quarter (valid after B2)

    const int blk = (blockIdx.x & 7) * 512 + (blockIdx.x >> 3);  // XCD-bijective
    const int b  = blk >> 10;
    const int wr = (blk >> 5) & 31;
    const int wc = blk & 31;

    // ---- stage input window into LDS ----
    if constexpr (STAGE == 0) {
        int n = tid >> 2, piece = tid & 3;
        int ph = wr * 8 + (n >> 3), pw = wc * 8 + (n & 7);
        const bf16* src = xin + ((size_t)b * 65536 + (size_t)ph * 256 + pw) * 128;
#pragma unroll
        for (int k = 0; k < 4; ++k) {
            int cc = (k * 4 + piece) * 8;
            bf16x8 v = *(const bf16x8*)(src + cc);
            *(bf16x8*)&s_x[(n * 128 + cc) ^ ((n & 15) << 3)] = v;
        }
    } else {
        const bf16* src = xin + ((size_t)b * 65536 + (size_t)(wr * 32 + wc) * 64) * 128;
#pragma unroll
        for (int k = 0; k < 4; ++k) {
            int g = k * 256 + tid;
            int n = g >> 4, cc = (g & 15) * 8;
            bf16x8 v = *(const bf16x8*)(src + g * 8);
            *(bf16x8*)&s_x[(n * 128 + cc) ^ ((n & 15) << 3)] = v;
        }
    }

    __syncthreads();   // B1

    // ---- pass Q: 2 tiles, scatter to exq, fragments to regs ----
    bf16x8 qb[4];
    {
        f32x4 acc[4][2];
#pragma unroll
        for (int mt = 0; mt < 4; ++mt)
#pragma unroll
            for (int t = 0; t < 2; ++t) acc[mt][t] = (f32x4){0.f, 0.f, 0.f, 0.f};
        bf16x8 wB[2][4];
#pragma unroll
        for (int t = 0; t < 2; ++t) {
            int co = wv * 32 + t * 16 + lr;
            const bf16* rp = wqkvT + co * 128 + lg * 8;
#pragma unroll
            for (int ks = 0; ks < 4; ++ks) wB[t][ks] = *(const bf16x8*)(rp + ks * 32);
        }
#pragma unroll
        for (int ks = 0; ks < 4; ++ks) {
            bf16x8 a[4];
#pragma unroll
            for (int mt = 0; mt < 4; ++mt) {
                int n = mt * 16 + lr;
                a[mt] = *(const bf16x8*)&s_x[(n * 128 + ks * 32 + lg * 8) ^ ((n & 15) << 3)];
            }
#pragma unroll
            for (int mt = 0; mt < 4; ++mt)
#pragma unroll
                for (int t = 0; t < 2; ++t)
                    acc[mt][t] = MFMA16(a[mt], wB[t][ks], acc[mt][t]);
        }
#pragma unroll
        for (int t = 0; t < 2; ++t) {
            float bias = b_qkv[wv * 32 + t * 16 + lr];
            int d = t * 16 + lr;
#pragma unroll
            for (int mt = 0; mt < 4; ++mt) {
                int n0 = mt * 16 + lg * 4;
#pragma unroll
                for (int r = 0; r < 4; ++r) {
                    int n = n0 + r;
                    exq[n * 32 + (d ^ QKSWZ(n))] = (bf16)(acc[mt][t][r] + bias);
                }
            }
        }
        LGKM0();
#pragma unroll
        for (int t = 0; t < 4; ++t) {
            int m = t * 16 + lr;
            qb[t] = *(const bf16x8*)&exq[m * 32 + ((lg * 8) ^ QKSWZ(m))];
        }
        LGKM0();   // qb landed before k overwrites quarter
    }

    // ---- pass K: 2 tiles, scatter to exq ----
    {
        f32x4 acc[4][2];
#pragma unroll
        for (int mt = 0; mt < 4; ++mt)
#pragma unroll
            for (int t = 0; t < 2; ++t) acc[mt][t] = (f32x4){0.f, 0.f, 0.f, 0.f};
        bf16x8 wB[2][4];
#pragma unroll
        for (int t = 0; t < 2; ++t) {
            int co = 128 + wv * 32 + t * 16 + lr;
            const bf16* rp = wqkvT + co * 128 + lg * 8;
#pragma unroll
            for (int ks = 0; ks < 4; ++ks) wB[t][ks] = *(const bf16x8*)(rp + ks * 32);
        }
#pragma unroll
        for (int ks = 0; ks < 4; ++ks) {
            bf16x8 a[4];
#pragma unroll
            for (int mt = 0; mt < 4; ++mt) {
                int n = mt * 16 + lr;
                a[mt] = *(const bf16x8*)&s_x[(n * 128 + ks * 32 + lg * 8) ^ ((n & 15) << 3)];
            }
#pragma unroll
            for (int mt = 0; mt < 4; ++mt)
#pragma unroll
                for (int t = 0; t < 2; ++t)
                    acc[mt][t] = MFMA16(a[mt], wB[t][ks], acc[mt][t]);
        }
#pragma unroll
        for (int t = 0; t < 2; ++t) {
            float bias = b_qkv[128 + wv * 32 + t * 16 + lr];
            int d = t * 16 + lr;
#pragma unroll
            for (int mt = 0; mt < 4; ++mt) {
                int n0 = mt * 16 + lg * 4;
#pragma unroll
                for (int r = 0; r < 4; ++r) {
                    int n = n0 + r;
                    exq[n * 32 + (d ^ QKSWZ(n))] = (bf16)(acc[mt][t][r] + bias);
                }
            }
        }
    }

    // residual -> registers (before s_x quarters get overwritten by vT)
    bf16x4 resr[2][4];
#pragma unroll
    for (int ct = 0; ct < 2; ++ct)
#pragma unroll
        for (int nt = 0; nt < 4; ++nt) {
            int n = nt * 16 + lr;
            int c0 = wv * 32 + ct * 16 + lg * 4;
            resr[ct][nt] = *(const bf16x4*)&s_x[(n * 128 + c0) ^ ((n & 15) << 3)];
        }

    // ---- pass V: 2 tiles (held briefly), flush to s_x quarter after B2 ----
    f32x4 accV[4][2];
    {
#pragma unroll
        for (int mt = 0; mt < 4; ++mt)
#pragma unroll
            for (int t = 0; t < 2; ++t) accV[mt][t] = (f32x4){0.f, 0.f, 0.f, 0.f};
        bf16x8 wB[2][4];
#pragma unroll
        for (int t = 0; t < 2; ++t) {
            int co = 256 + wv * 32 + t * 16 + lr;
            const bf16* rp = wqkvT + co * 128 + lg * 8;
#pragma unroll
            for (int ks = 0; ks < 4; ++ks) wB[t][ks] = *(const bf16x8*)(rp + ks * 32);
        }
#pragma unroll
        for (int ks = 0; ks < 4; ++ks) {
            bf16x8 a[4];
#pragma unroll
            for (int mt = 0; mt < 4; ++mt) {
                int n = mt * 16 + lr;
                a[mt] = *(const bf16x8*)&s_x[(n * 128 + ks * 32 + lg * 8) ^ ((n & 15) << 3)];
            }
#pragma unroll
            for (int mt = 0; mt < 4; ++mt)
#pragma unroll
                for (int t = 0; t < 2; ++t)
                    accV[mt][t] = MFMA16(a[mt], wB[t][ks], accV[mt][t]);
        }
    }

    // bias fragments -> registers (coalesced 16B loads, L1-hot; overlap w/ MFMA)
    bf16x8 bi[8];
    {
        const bf16* bpp = biasC + wv * 4096 + lane * 8;
#pragma unroll
        for (int i = 0; i < 8; ++i)
            bi[i] = *(const bf16x8*)(bpp + i * 512);
    }

    __syncthreads();   // B2: all s_x GEMM/residual reads done; quarters free

    // vT scatter -> own s_x quarter [d][64] swz (frees accV before softmax)
#pragma unroll
    for (int t = 0; t < 2; ++t) {
        float bias = b_qkv[256 + wv * 32 + t * 16 + lr];
        int d = t * 16 + lr;
#pragma unroll
        for (int mt = 0; mt < 4; ++mt) {
            bf16x4 v4;
#pragma unroll
            for (int r = 0; r < 4; ++r) v4[r] = (bf16)(accV[mt][t][r] + bias);
            int idx = (d * 64 + mt * 16 + lg * 4) ^ ((d & 7) << 3);
            *(bf16x4*)&exv[idx] = v4;
        }
    }

    // ---- S^T = K * Q^T (wave-local) ----
    f32x4 sacc[4][4];
#pragma unroll
    for (int mt = 0; mt < 4; ++mt)
#pragma unroll
        for (int nt = 0; nt < 4; ++nt) sacc[mt][nt] = (f32x4){0.f, 0.f, 0.f, 0.f};
#pragma unroll
    for (int mt = 0; mt < 4; ++mt) {
        int m = mt * 16 + lr;
        bf16x8 ka = *(const bf16x8*)&exq[m * 32 + ((lg * 8) ^ QKSWZ(m))];
#pragma unroll
        for (int nt = 0; nt < 4; ++nt)
            sacc[mt][nt] = MFMA16(ka, qb[nt], sacc[mt][nt]);
    }

    // softmax over m (scale 0.5 + precomputed bias fragment, pure FMA)
    float inv[4];
#pragma unroll
    for (int nt = 0; nt < 4; ++nt) {
        float mx = -1e30f;
#pragma unroll
        for (int mt = 0; mt < 4; ++mt)
#pragma unroll
            for (int r = 0; r < 4; ++r) {
                int e = (mt * 4 + nt) * 4 + r;
                float lgt = sacc[mt][nt][r] * 0.5f + (float)bi[e >> 3][e & 7];
                sacc[mt][nt][r] = lgt;
                mx = fmaxf(mx, lgt);
            }
        mx = fmaxf(mx, __shfl_xor(mx, 16));
        mx = fmaxf(mx, __shfl_xor(mx, 32));
        float sum = 0.f;
#pragma unroll
        for (int mt = 0; mt < 4; ++mt)
#pragma unroll
            for (int r = 0; r < 4; ++r) {
                float p = __expf(sacc[mt][nt][r] - mx);
                sacc[mt][nt][r] = p;
                sum += p;
            }
        sum += __shfl_xor(sum, 16);
        sum += __shfl_xor(sum, 32);
        inv[nt] = 1.f / sum;
    }
    LGKM0();   // ka reads + vT stores landed

    // v fragments -> registers
    bf16x8 va[2][2];
#pragma unroll
    for (int dt = 0; dt < 2; ++dt) {
        int d = dt * 16 + lr;
#pragma unroll
        for (int ks = 0; ks < 2; ++ks)
            va[dt][ks] = *(const bf16x8*)&exv[(d * 64 + ks * 32 + lg * 8) ^ ((d & 7) << 3)];
    }

    __syncthreads();   // B3: all waves' va preloads done -> s_x fully dead

    // ---- PV via P halves through exq: out^T[d][n] ----
    f32x4 oacc[2][4];
#pragma unroll
    for (int dt = 0; dt < 2; ++dt)
#pragma unroll
        for (int nt = 0; nt < 4; ++nt) oacc[dt][nt] = (f32x4){0.f, 0.f, 0.f, 0.f};
#pragma unroll
    for (int ks = 0; ks < 2; ++ks) {
#pragma unroll
        for (int nt = 0; nt < 4; ++nt) {
            int n = nt * 16 + lr;
#pragma unroll
            for (int mh = 0; mh < 2; ++mh) {
                int mt = ks * 2 + mh;
                bf16x4 v4;
#pragma unroll
                for (int r = 0; r < 4; ++r) v4[r] = (bf16)(sacc[mt][nt][r] * inv[nt]);
                int off = (mh * 16 + lg * 4) ^ ((n & 3) << 3);
                *(bf16x4*)&exq[n * 32 + off] = v4;
            }
        }
        LGKM0();
        bf16x8 pb[4];
#pragma unroll
        for (int nt = 0; nt < 4; ++nt) {
            int n = nt * 16 + lr;
            pb[nt] = *(const bf16x8*)&exq[n * 32 + ((lg * 8) ^ ((n & 3) << 3))];
        }
#pragma unroll
        for (int dt = 0; dt < 2; ++dt)
#pragma unroll
            for (int nt = 0; nt < 4; ++nt)
                oacc[dt][nt] = MFMA16(va[dt][ks], pb[nt], oacc[dt][nt]);
        LGKM0();   // pb reads landed before next half overwrites
    }

    // attn output -> s_x as [n][c] (safe: B3 passed; exq is wave-local)
#pragma unroll
    for (int dt = 0; dt < 2; ++dt)
#pragma unroll
        for (int nt = 0; nt < 4; ++nt) {
            int n = nt * 16 + lr;
            int c0 = wv * 32 + dt * 16 + lg * 4;
            bf16x4 v4;
#pragma unroll
            for (int r = 0; r < 4; ++r) v4[r] = (bf16)oacc[dt][nt][r];
            int idx = (n * 128 + c0) ^ ((n & 15) << 3);
            *(bf16x4*)&s_x[idx] = v4;
        }

    __syncthreads();   // B4: attnout complete

    // ---- proj: x1^T[co][n] = sum_c wproj[c][co] * attn[n][c] ----
    f32x4 pacc[2][4];
#pragma unroll
    for (int ct = 0; ct < 2; ++ct)
#pragma unroll
        for (int nt = 0; nt < 4; ++nt) pacc[ct][nt] = (f32x4){0.f, 0.f, 0.f, 0.f};
#pragma unroll
    for (int ks = 0; ks < 4; ++ks) {
        bf16x8 wa[2], ab[4];
#pragma unroll
        for (int ct = 0; ct < 2; ++ct) {
            int co = wv * 32 + ct * 16 + lr;
            wa[ct] = *(const bf16x8*)(wprojT + co * 128 + ks * 32 + lg * 8);
        }
#pragma unroll
        for (int nt = 0; nt < 4; ++nt) {
            int n = nt * 16 + lr;
            ab[nt] = *(const bf16x8*)&s_x[(n * 128 + ks * 32 + lg * 8) ^ ((n & 15) << 3)];
        }
#pragma unroll
        for (int ct = 0; ct < 2; ++ct)
#pragma unroll
            for (int nt = 0; nt < 4; ++nt)
                pacc[ct][nt] = MFMA16(wa[ct], ab[nt], pacc[ct][nt]);
    }

    // ---- epilogue: residual + bias; pool partials; DIRECT register stores ----
    float bp[2][4];
#pragma unroll
    for (int ct = 0; ct < 2; ++ct)
#pragma unroll
        for (int r = 0; r < 4; ++r) bp[ct][r] = b_proj[wv * 32 + ct * 16 + lg * 4 + r];

    float ps[2][4], pm[2][4];
    if constexpr (STAGE == 1) {
#pragma unroll
        for (int ct = 0; ct < 2; ++ct)
#pragma unroll
            for (int r = 0; r < 4; ++r) { ps[ct][r] = 0.f; pm[ct][r] = -1e30f; }
    }

#pragma unroll
    for (int ct = 0; ct < 2; ++ct)
#pragma unroll
        for (int nt = 0; nt < 4; ++nt) {
            int n = nt * 16 + lr;
            int c0 = wv * 32 + ct * 16 + lg * 4;
            bf16x4 o;
#pragma unroll
            for (int r = 0; r < 4; ++r) {
                float v = (float)resr[ct][nt][r] + bp[ct][r] + pacc[ct][nt][r];
                o[r] = (bf16)v;
                if constexpr (STAGE == 1) {
                    ps[ct][r] += v;
                    pm[ct][r] = fmaxf(pm[ct][r], v);
                }
            }
            size_t pix;
            if constexpr (STAGE == 0) {
                int ph = wr * 8 + (n >> 3), pw = wc * 8 + (n & 7);
                int gw = ((ph & 31) << 5) + (pw & 31);
                int nn = ((ph >> 5) << 3) + (pw >> 5);
                pix = (size_t)b * 65536 + (size_t)gw * 64 + nn;
            } else {
                pix = (size_t)b * 65536 + (size_t)(wr * 32 + wc) * 64 + n;
            }
            *(bf16x4*)(xout + pix * 128 + c0) = o;
        }

    if constexpr (STAGE == 1) {
        const int w = blk & 1023;
        float* prow_s = psum + (size_t)w * 512 + b * 128;
        float* prow_m = pmax + (size_t)w * 512 + b * 128;
#pragma unroll
        for (int ct = 0; ct < 2; ++ct) {
            f32x4 sv, mv;
#pragma unroll
            for (int r = 0; r < 4; ++r) {
                float s = ps[ct][r], m = pm[ct][r];
#pragma unroll
                for (int o = 1; o < 16; o <<= 1) {
                    s += __shfl_xor(s, o);
                    m = fmaxf(m, __shfl_xor(m, o));
                }
                sv[r] = s; mv[r] = m;
            }
            if (lr == 0) {
                int cbase = wv * 32 + ct * 16 + lg * 4;
                *(f32x4*)&prow_s[cbase] = sv;     // 16B vector store (full lines)
                *(f32x4*)&prow_m[cbase] = mv;
            }
        }
    }
}

// ---- reduce pooling partials: avg/mx[b*128+c] over 1024 windows ----
__global__ __launch_bounds__(64) void reduce_kernel(const float* __restrict__ psum,
                                                    const float* __restrict__ pmax,
                                                    float* __restrict__ avg,
                                                    float* __restrict__ mx)
{
    int bc = blockIdx.x;        // 0..511
    int t = threadIdx.x;        // 0..63
    float s = 0.f, m = -1e30f;
#pragma unroll
    for (int k = 0; k < 16; ++k) {
        size_t w = t + k * 64;
        s += psum[w * 512 + bc];
        m = fmaxf(m, pmax[w * 512 + bc]);
    }
#pragma unroll
    for (int o = 1; o < 64; o <<= 1) {
        s += __shfl_xor(s, o);
        m = fmaxf(m, __shfl_xor(m, o));
    }
    if (t == 0) { avg[bc] = s * (1.f / 65536.f); mx[bc] = m; }
}

// ---- gate = sigmoid( (relu(avg@W1)+relu(mx@W1)) @ W2 ) ----
__global__ void gate_kernel(const float* __restrict__ avg, const float* __restrict__ mxp,
                            const float* __restrict__ w1, const float* __restrict__ w2,
                            float* __restrict__ gate)
{
    __shared__ float la[512], lm[512], s1[512];
    int t = threadIdx.x;
    la[t] = avg[t];
    lm[t] = mxp[t];
    __syncthreads();
    int b = t >> 7, co = t & 127;
    float a1 = 0.f, m1 = 0.f;
    for (int c = 0; c < 128; ++c) {
        float w = w1[c * 128 + co];
        a1 += la[b * 128 + c] * w;
        m1 += lm[b * 128 + c] * w;
    }
    s1[t] = fmaxf(a1, 0.f) + fmaxf(m1, 0.f);
    __syncthreads();
    float g = 0.f;
    for (int c = 0; c < 128; ++c) g += s1[b * 128 + c] * w2[c * 128 + co];
    gate[t] = 1.f / (1.f + __expf(-g));
}

// ---- k4: x2 (grid-major bf16) * gate -> out NCHW fp32 (tiled LDS transpose) ----
__global__ __launch_bounds__(256) void tout_kernel(const bf16* __restrict__ x2,
                                                   const float* __restrict__ gate,
                                                   float* __restrict__ out)
{
    __shared__ float s[128 * 68];
    __shared__ float sg[128];
    const int blk = blockIdx.x;            // b*1024 + chunk(64px within one row)
    const int b = blk >> 10;
    const int chunk = blk & 1023;
    const int ph = chunk >> 2, pw0 = (chunk & 3) * 64;
    const int gwb = (ph & 31) << 5;
    const int nb  = ((ph >> 5) << 3) + (pw0 >> 5);
    const int t = threadIdx.x;
    if (t < 128) sg[t] = gate[b * 128 + t];
    __syncthreads();
    const bf16* base = x2 + (size_t)b * 65536 * 128;
#pragma unroll
    for (int i = 0; i < 4; ++i) {
        int idx8 = t + i * 256;            // 0..1023 = 64px * 16 chunks
        int px = idx8 >> 4, c8 = idx8 & 15;
        size_t pi = (size_t)(gwb + (px & 31)) * 64 + nb + (px >> 5);
        bf16x8 v = *(const bf16x8*)(base + pi * 128 + c8 * 8);
        int pxs = px ^ ((c8 & 7) << 3);
#pragma unroll
        for (int j = 0; j < 8; ++j) {
            int c = c8 * 8 + j;
            s[c * 68 + pxs] = (float)v[j] * sg[c];
        }
    }
    __syncthreads();
    int cg = t >> 4, pl = (t & 15) * 4;
#pragma unroll
    for (int i = 0; i < 8; ++i) {
        int c = cg + i * 16;
        int pp = pl ^ (((c >> 3) & 7) << 3);
        f32x4 w = *(const f32x4*)&s[c * 68 + pp];
        *(f32x4*)&out[((size_t)(b * 128 + c)) * 65536 + ph * 256 + pw0 + pl] = w;
    }
}

extern "C" void kernel_launch(void* const* d_in, const int* in_sizes, int n_in,
                              void* d_out, int out_size, void* d_ws, size_t ws_size,
                              hipStream_t stream)
{
    const float* x      = (const float*)d_in[0];
    const float* w_qkv  = (const float*)d_in[1];
    const float* b_qkv  = (const float*)d_in[2];
    const float* w_proj = (const float*)d_in[3];
    const float* b_proj = (const float*)d_in[4];
    const float* rpb    = (const float*)d_in[5];
    const float* cf_w1  = (const float*)d_in[6];
    const float* cf_w2  = (const float*)d_in[7];
    float* out = (float*)d_out;

    char* ws = (char*)d_ws;
    // ws[0:64MB] = xT (bf16 linear NHWC, dead after attn<0>)
    //            = x2 (bf16 grid-major, written by attn<1>, read by tout)
    bf16* xT = (bf16*)ws;
    bf16* x2 = (bf16*)ws;
    char* tail = ws + 67108864;                      // 64 MB
    bf16*  wqkvT  = (bf16*)tail;                     // 96 KB
    bf16*  wprojT = (bf16*)(tail + 98304);           // 32 KB
    float* psum   = (float*)(tail + 131072);         // 2 MB  (1024 windows x 512)
    float* pmax   = (float*)(tail + 131072 + 2097152);   // 2 MB
    float* avg    = (float*)(tail + 131072 + 4194304);   // 2 KB
    float* mxp    = (float*)(tail + 131072 + 4196352);   // 2 KB
    float* gate   = (float*)(tail + 131072 + 4198400);   // 2 KB
    bf16*  biasC  = (bf16*)(tail + 131072 + 4200448);    // 32 KB
    bf16*  x1T    = (bf16*)d_out;                    // grid-major bf16, 64MB, dead after attn<1>

    tin_kernel<<<4096, 256, 0, stream>>>(x, xT);
    wconv_kernel<<<256, 256, 0, stream>>>(w_qkv, w_proj, rpb, wqkvT, wprojT, biasC);
    attn_kernel<0><<<4096, 256, 0, stream>>>(xT,  x1T, wqkvT, wprojT,
                                             b_qkv, b_proj, biasC, nullptr, nullptr);
    attn_kernel<1><<<4096, 256, 0, stream>>>(x1T, x2,  wqkvT, wprojT,
                                             b_qkv, b_proj, biasC, psum, pmax);
    reduce_kernel<<<512, 64, 0, stream>>>(psum, pmax, avg, mxp);
    gate_kernel<<<1, 512, 0, stream>>>(avg, mxp, cf_w1, cf_w2, gate);
    tout_kernel<<<4096, 256, 0, stream>>>(x2, gate, out);
}

// Round 20
// 286.716 us; speedup vs baseline: 1.6548x; 1.0127x over previous
//
#include <hip/hip_runtime.h>
#include <hip/hip_bf16.h>
#include <stdint.h>

typedef __bf16 bf16;
typedef bf16 bf16x8 __attribute__((ext_vector_type(8)));
typedef bf16 bf16x4 __attribute__((ext_vector_type(4)));
typedef float f32x4 __attribute__((ext_vector_type(4)));

#define MFMA16(a, b, c) __builtin_amdgcn_mfma_f32_16x16x32_bf16((a), (b), (c), 0, 0, 0)
#define QKSWZ(n) ((((n) >> 2) & 3) << 3)
#define LGKM0() do { asm volatile("s_waitcnt lgkmcnt(0)" ::: "memory"); \
                     __builtin_amdgcn_sched_barrier(0); } while (0)

// ---- k0: x [B,C,H,W] fp32 -> xT [B,H,W,C] bf16 linear (tiled LDS transpose) ----
__global__ __launch_bounds__(256) void tin_kernel(const float* __restrict__ x,
                                                  bf16* __restrict__ xT)
{
    __shared__ float s[128 * 65];
    const int blk = blockIdx.x;            // b*1024 + pxchunk
    const int b = blk >> 10;
    const int px0 = (blk & 1023) * 64;
    const int tid = threadIdx.x;
    {
        int c0 = tid >> 6, pxl = tid & 63;
        const float* src = x + (size_t)b * 8388608 + px0 + pxl;
#pragma unroll
        for (int i = 0; i < 32; ++i) {
            int c = c0 + i * 4;
            s[c * 65 + pxl] = src[(size_t)c * 65536];
        }
    }
    __syncthreads();
    int px = tid >> 2, piece = tid & 3;
    bf16* dstp = xT + ((size_t)b * 65536 + px0 + px) * 128;
#pragma unroll
    for (int k = 0; k < 4; ++k) {
        bf16x8 v8;
        int cb = (k * 4 + piece) * 8;
#pragma unroll
        for (int j = 0; j < 8; ++j) v8[j] = (bf16)s[(cb + j) * 65 + px];
        *(bf16x8*)(dstp + cb) = v8;
    }
}

// ---- convert+transpose weights to bf16 + precompute per-lane bias fragments ----
// biasC[h*4096 + i*512 + lane*8 + s]: bias for softmax element e=i*8+s of lane,
// head h, in the sacc fragment order (e = (mt*4+nt)*4+r). Same for all windows.
__global__ void wconv_kernel(const float* __restrict__ w_qkv,
                             const float* __restrict__ w_proj,
                             const float* __restrict__ rpb,
                             bf16* __restrict__ wqkvT,
                             bf16* __restrict__ wprojT,
                             bf16* __restrict__ biasC)
{
    int id = blockIdx.x * 256 + threadIdx.x;
    if (id < 16384) {
        int s = id & 7, lane = (id >> 3) & 63, i = (id >> 9) & 7, h = id >> 12;
        int e = i * 8 + s;
        int mt = e >> 4, nt = (e >> 2) & 3, r = e & 3;
        int n = nt * 16 + (lane & 15);
        int m = mt * 16 + (lane >> 4) * 4 + r;
        int rel = ((n >> 3) - (m >> 3) + 7) * 15 + ((n & 7) - (m & 7) + 7);
        biasC[id] = (bf16)rpb[rel * 4 + h];
    }
    if (id < 49152) {                       // 384*128
        int co = id >> 7, c = id & 127;
        wqkvT[id] = (bf16)w_qkv[c * 384 + co];
    } else {
        int id2 = id - 49152;               // 128*128
        int co = id2 >> 7, c = id2 & 127;
        wprojT[id2] = (bf16)w_proj[c * 128 + co];
    }
}

// ---- fused window/grid relative attention, one 8x8 window per block ----
// Own-head decomposition, 3-pass QKV. Q/K passes use SWAPPED-operand MFMA
// (A=weight rows, B=x) so D = qkv^T[d][n]: each lane holds 4 consecutive d at
// fixed n -> q/k scatter into [n][32] is bf16x4 VECTOR stores (was 32 scalar
// ds_write_b16/pass; kills most of the 7.3M bank conflicts). V pass keeps the
// original orientation (its [d][64] scatter is already vectorized).
// Per-wave 4KB exchange quarters; 4 block barriers; direct-register epilogue;
// precomputed bias fragments. LDS 32KB, launch_bounds(256,3): VGPR~84.
// R17/R18: (256,4)/(256,5) clamp VGPR to 64/48 and spill. R15: multi-window
// loops regress badly.
// STAGE 0: window partition; in = xT linear, out = x1T grid-major (scatter)
// STAGE 1: grid partition; in/out grid-major CONTIG 16KB + pooling partials
template<int STAGE>
__global__ __launch_bounds__(256, 3)
void attn_kernel(const bf16* __restrict__ xin, bf16* __restrict__ xout,
                 const bf16* __restrict__ wqkvT, const bf16* __restrict__ wprojT,
                 const float* __restrict__ b_qkv, const float* __restrict__ b_proj,
                 const bf16* __restrict__ biasC,
                 float* __restrict__ psum, float* __restrict__ pmax)
{
    __shared__ __align__(16) bf16 s_x[8192];   // input [n][c] -> vT quarters -> attnout
    __shared__ __align__(16) bf16 s_ex[8192];  // per-wave 4KB: q -> k -> P halves

    const int tid = threadIdx.x;
    const int lane = tid & 63;
    const int wv = tid >> 6;     // wave = head
    const int lr = lane & 15;
    const int lg = lane >> 4;
    bf16* exq = s_ex + wv * 2048;              // per-wave exchange quarter
    bf16* exv = s_x + wv * 2048;               // per-wave vT quarter (valid after B2)

    const int blk = (blockIdx.x & 7) * 512 + (blockIdx.x >> 3);  // XCD-bijective
    const int b  = blk >> 10;
    const int wr = (blk >> 5) & 31;
    const int wc = blk & 31;

    // ---- stage input window into LDS ----
    if constexpr (STAGE == 0) {
        int n = tid >> 2, piece = tid & 3;
        int ph = wr * 8 + (n >> 3), pw = wc * 8 + (n & 7);
        const bf16* src = xin + ((size_t)b * 65536 + (size_t)ph * 256 + pw) * 128;
#pragma unroll
        for (int k = 0; k < 4; ++k) {
            int cc = (k * 4 + piece) * 8;
            bf16x8 v = *(const bf16x8*)(src + cc);
            *(bf16x8*)&s_x[(n * 128 + cc) ^ ((n & 15) << 3)] = v;
        }
    } else {
        const bf16* src = xin + ((size_t)b * 65536 + (size_t)(wr * 32 + wc) * 64) * 128;
#pragma unroll
        for (int k = 0; k < 4; ++k) {
            int g = k * 256 + tid;
            int n = g >> 4, cc = (g & 15) * 8;
            bf16x8 v = *(const bf16x8*)(src + g * 8);
            *(bf16x8*)&s_x[(n * 128 + cc) ^ ((n & 15) << 3)] = v;
        }
    }

    __syncthreads();   // B1

    // ---- pass Q (swapped operands): acc[t][nt] = q^T[d][n]; vector scatter ----
    bf16x8 qb[4];
    {
        f32x4 acc[2][4];
#pragma unroll
        for (int t = 0; t < 2; ++t)
#pragma unroll
            for (int nt = 0; nt < 4; ++nt) acc[t][nt] = (f32x4){0.f, 0.f, 0.f, 0.f};
        bf16x8 wA[2][4];
#pragma unroll
        for (int t = 0; t < 2; ++t) {
            int co = wv * 32 + t * 16 + lr;
            const bf16* rp = wqkvT + co * 128 + lg * 8;
#pragma unroll
            for (int ks = 0; ks < 4; ++ks) wA[t][ks] = *(const bf16x8*)(rp + ks * 32);
        }
#pragma unroll
        for (int ks = 0; ks < 4; ++ks) {
            bf16x8 xb[4];
#pragma unroll
            for (int nt = 0; nt < 4; ++nt) {
                int n = nt * 16 + lr;
                xb[nt] = *(const bf16x8*)&s_x[(n * 128 + ks * 32 + lg * 8) ^ ((n & 15) << 3)];
            }
#pragma unroll
            for (int t = 0; t < 2; ++t)
#pragma unroll
                for (int nt = 0; nt < 4; ++nt)
                    acc[t][nt] = MFMA16(wA[t][ks], xb[nt], acc[t][nt]);
        }
#pragma unroll
        for (int t = 0; t < 2; ++t) {
            f32x4 bq = *(const f32x4*)&b_qkv[wv * 32 + t * 16 + lg * 4];
            int d0 = t * 16 + lg * 4;
#pragma unroll
            for (int nt = 0; nt < 4; ++nt) {
                int n = nt * 16 + lr;
                bf16x4 v4;
#pragma unroll
                for (int r = 0; r < 4; ++r) v4[r] = (bf16)(acc[t][nt][r] + bq[r]);
                *(bf16x4*)&exq[n * 32 + (d0 ^ QKSWZ(n))] = v4;
            }
        }
        LGKM0();
#pragma unroll
        for (int t = 0; t < 4; ++t) {
            int m = t * 16 + lr;
            qb[t] = *(const bf16x8*)&exq[m * 32 + ((lg * 8) ^ QKSWZ(m))];
        }
        LGKM0();   // qb landed before k overwrites quarter
    }

    // ---- pass K (swapped operands): vector scatter to exq ----
    {
        f32x4 acc[2][4];
#pragma unroll
        for (int t = 0; t < 2; ++t)
#pragma unroll
            for (int nt = 0; nt < 4; ++nt) acc[t][nt] = (f32x4){0.f, 0.f, 0.f, 0.f};
        bf16x8 wA[2][4];
#pragma unroll
        for (int t = 0; t < 2; ++t) {
            int co = 128 + wv * 32 + t * 16 + lr;
            const bf16* rp = wqkvT + co * 128 + lg * 8;
#pragma unroll
            for (int ks = 0; ks < 4; ++ks) wA[t][ks] = *(const bf16x8*)(rp + ks * 32);
        }
#pragma unroll
        for (int ks = 0; ks < 4; ++ks) {
            bf16x8 xb[4];
#pragma unroll
            for (int nt = 0; nt < 4; ++nt) {
                int n = nt * 16 + lr;
                xb[nt] = *(const bf16x8*)&s_x[(n * 128 + ks * 32 + lg * 8) ^ ((n & 15) << 3)];
            }
#pragma unroll
            for (int t = 0; t < 2; ++t)
#pragma unroll
                for (int nt = 0; nt < 4; ++nt)
                    acc[t][nt] = MFMA16(wA[t][ks], xb[nt], acc[t][nt]);
        }
#pragma unroll
        for (int t = 0; t < 2; ++t) {
            f32x4 bq = *(const f32x4*)&b_qkv[128 + wv * 32 + t * 16 + lg * 4];
            int d0 = t * 16 + lg * 4;
#pragma unroll
            for (int nt = 0; nt < 4; ++nt) {
                int n = nt * 16 + lr;
                bf16x4 v4;
#pragma unroll
                for (int r = 0; r < 4; ++r) v4[r] = (bf16)(acc[t][nt][r] + bq[r]);
                *(bf16x4*)&exq[n * 32 + (d0 ^ QKSWZ(n))] = v4;
            }
        }
    }

    // residual -> registers (before s_x quarters get overwritten by vT)
    bf16x4 resr[2][4];
#pragma unroll
    for (int ct = 0; ct < 2; ++ct)
#pragma unroll
        for (int nt = 0; nt < 4; ++nt) {
            int n = nt * 16 + lr;
            int c0 = wv * 32 + ct * 16 + lg * 4;
            resr[ct][nt] = *(const bf16x4*)&s_x[(n * 128 + c0) ^ ((n & 15) << 3)];
        }

    // ---- pass V (original orientation): acc[m][t], flush to s_x quarter ----
    f32x4 accV[4][2];
    {
#pragma unroll
        for (int mt = 0; mt < 4; ++mt)
#pragma unroll
            for (int t = 0; t < 2; ++t) accV[mt][t] = (f32x4){0.f, 0.f, 0.f, 0.f};
        bf16x8 wB[2][4];
#pragma unroll
        for (int t = 0; t < 2; ++t) {
            int co = 256 + wv * 32 + t * 16 + lr;
            const bf16* rp = wqkvT + co * 128 + lg * 8;
#pragma unroll
            for (int ks = 0; ks < 4; ++ks) wB[t][ks] = *(const bf16x8*)(rp + ks * 32);
        }
#pragma unroll
        for (int ks = 0; ks < 4; ++ks) {
            bf16x8 a[4];
#pragma unroll
            for (int mt = 0; mt < 4; ++mt) {
                int n = mt * 16 + lr;
                a[mt] = *(const bf16x8*)&s_x[(n * 128 + ks * 32 + lg * 8) ^ ((n & 15) << 3)];
            }
#pragma unroll
            for (int mt = 0; mt < 4; ++mt)
#pragma unroll
                for (int t = 0; t < 2; ++t)
                    accV[mt][t] = MFMA16(a[mt], wB[t][ks], accV[mt][t]);
        }
    }

    // bias fragments -> registers (coalesced 16B loads, L1-hot; overlap w/ MFMA)
    bf16x8 bi[8];
    {
        const bf16* bpp = biasC + wv * 4096 + lane * 8;
#pragma unroll
        for (int i = 0; i < 8; ++i)
            bi[i] = *(const bf16x8*)(bpp + i * 512);
    }

    __syncthreads();   // B2: all s_x GEMM/residual reads done; quarters free

    // vT scatter -> own s_x quarter [d][64] swz (frees accV before softmax)
#pragma unroll
    for (int t = 0; t < 2; ++t) {
        float bias = b_qkv[256 + wv * 32 + t * 16 + lr];
        int d = t * 16 + lr;
#pragma unroll
        for (int mt = 0; mt < 4; ++mt) {
            bf16x4 v4;
#pragma unroll
            for (int r = 0; r < 4; ++r) v4[r] = (bf16)(accV[mt][t][r] + bias);
            int idx = (d * 64 + mt * 16 + lg * 4) ^ ((d & 7) << 3);
            *(bf16x4*)&exv[idx] = v4;
        }
    }

    // ---- S^T = K * Q^T (wave-local) ----
    f32x4 sacc[4][4];
#pragma unroll
    for (int mt = 0; mt < 4; ++mt)
#pragma unroll
        for (int nt = 0; nt < 4; ++nt) sacc[mt][nt] = (f32x4){0.f, 0.f, 0.f, 0.f};
#pragma unroll
    for (int mt = 0; mt < 4; ++mt) {
        int m = mt * 16 + lr;
        bf16x8 ka = *(const bf16x8*)&exq[m * 32 + ((lg * 8) ^ QKSWZ(m))];
#pragma unroll
        for (int nt = 0; nt < 4; ++nt)
            sacc[mt][nt] = MFMA16(ka, qb[nt], sacc[mt][nt]);
    }

    // softmax over m (scale 0.5 + precomputed bias fragment, pure FMA)
    float inv[4];
#pragma unroll
    for (int nt = 0; nt < 4; ++nt) {
        float mx = -1e30f;
#pragma unroll
        for (int mt = 0; mt < 4; ++mt)
#pragma unroll
            for (int r = 0; r < 4; ++r) {
                int e = (mt * 4 + nt) * 4 + r;
                float lgt = sacc[mt][nt][r] * 0.5f + (float)bi[e >> 3][e & 7];
                sacc[mt][nt][r] = lgt;
                mx = fmaxf(mx, lgt);
            }
        mx = fmaxf(mx, __shfl_xor(mx, 16));
        mx = fmaxf(mx, __shfl_xor(mx, 32));
        float sum = 0.f;
#pragma unroll
        for (int mt = 0; mt < 4; ++mt)
#pragma unroll
            for (int r = 0; r < 4; ++r) {
                float p = __expf(sacc[mt][nt][r] - mx);
                sacc[mt][nt][r] = p;
                sum += p;
            }
        sum += __shfl_xor(sum, 16);
        sum += __shfl_xor(sum, 32);
        inv[nt] = 1.f / sum;
    }
    LGKM0();   // ka reads + vT stores landed

    // v fragments -> registers
    bf16x8 va[2][2];
#pragma unroll
    for (int dt = 0; dt < 2; ++dt) {
        int d = dt * 16 + lr;
#pragma unroll
        for (int ks = 0; ks < 2; ++ks)
            va[dt][ks] = *(const bf16x8*)&exv[(d * 64 + ks * 32 + lg * 8) ^ ((d & 7) << 3)];
    }

    __syncthreads();   // B3: all waves' va preloads done -> s_x fully dead

    // ---- PV via P halves through exq: out^T[d][n] ----
    f32x4 oacc[2][4];
#pragma unroll
    for (int dt = 0; dt < 2; ++dt)
#pragma unroll
        for (int nt = 0; nt < 4; ++nt) oacc[dt][nt] = (f32x4){0.f, 0.f, 0.f, 0.f};
#pragma unroll
    for (int ks = 0; ks < 2; ++ks) {
#pragma unroll
        for (int nt = 0; nt < 4; ++nt) {
            int n = nt * 16 + lr;
#pragma unroll
            for (int mh = 0; mh < 2; ++mh) {
                int mt = ks * 2 + mh;
                bf16x4 v4;
#pragma unroll
                for (int r = 0; r < 4; ++r) v4[r] = (bf16)(sacc[mt][nt][r] * inv[nt]);
                int off = (mh * 16 + lg * 4) ^ ((n & 3) << 3);
                *(bf16x4*)&exq[n * 32 + off] = v4;
            }
        }
        LGKM0();
        bf16x8 pb[4];
#pragma unroll
        for (int nt = 0; nt < 4; ++nt) {
            int n = nt * 16 + lr;
            pb[nt] = *(const bf16x8*)&exq[n * 32 + ((lg * 8) ^ ((n & 3) << 3))];
        }
#pragma unroll
        for (int dt = 0; dt < 2; ++dt)
#pragma unroll
            for (int nt = 0; nt < 4; ++nt)
                oacc[dt][nt] = MFMA16(va[dt][ks], pb[nt], oacc[dt][nt]);
        LGKM0();   // pb reads landed before next half overwrites
    }

    // attn output -> s_x as [n][c] (safe: B3 passed; exq is wave-local)
#pragma unroll
    for (int dt = 0; dt < 2; ++dt)
#pragma unroll
        for (int nt = 0; nt < 4; ++nt) {
            int n = nt * 16 + lr;
            int c0 = wv * 32 + dt * 16 + lg * 4;
            bf16x4 v4;
#pragma unroll
            for (int r = 0; r < 4; ++r) v4[r] = (bf16)oacc[dt][nt][r];
            int idx = (n * 128 + c0) ^ ((n & 15) << 3);
            *(bf16x4*)&s_x[idx] = v4;
        }

    __syncthreads();   // B4: attnout complete

    // ---- proj: x1^T[co][n] = sum_c wproj[c][co] * attn[n][c] ----
    f32x4 pacc[2][4];
#pragma unroll
    for (int ct = 0; ct < 2; ++ct)
#pragma unroll
        for (int nt = 0; nt < 4; ++nt) pacc[ct][nt] = (f32x4){0.f, 0.f, 0.f, 0.f};
#pragma unroll
    for (int ks = 0; ks < 4; ++ks) {
        bf16x8 wa[2], ab[4];
#pragma unroll
        for (int ct = 0; ct < 2; ++ct) {
            int co = wv * 32 + ct * 16 + lr;
            wa[ct] = *(const bf16x8*)(wprojT + co * 128 + ks * 32 + lg * 8);
        }
#pragma unroll
        for (int nt = 0; nt < 4; ++nt) {
            int n = nt * 16 + lr;
            ab[nt] = *(const bf16x8*)&s_x[(n * 128 + ks * 32 + lg * 8) ^ ((n & 15) << 3)];
        }
#pragma unroll
        for (int ct = 0; ct < 2; ++ct)
#pragma unroll
            for (int nt = 0; nt < 4; ++nt)
                pacc[ct][nt] = MFMA16(wa[ct], ab[nt], pacc[ct][nt]);
    }

    // ---- epilogue: residual + bias; pool partials; DIRECT register stores ----
    float bp[2][4];
#pragma unroll
    for (int ct = 0; ct < 2; ++ct)
#pragma unroll
        for (int r = 0; r < 4; ++r) bp[ct][r] = b_proj[wv * 32 + ct * 16 + lg * 4 + r];

    float ps[2][4], pm[2][4];
    if constexpr (STAGE == 1) {
#pragma unroll
        for (int ct = 0; ct < 2; ++ct)
#pragma unroll
            for (int r = 0; r < 4; ++r) { ps[ct][r] = 0.f; pm[ct][r] = -1e30f; }
    }

#pragma unroll
    for (int ct = 0; ct < 2; ++ct)
#pragma unroll
        for (int nt = 0; nt < 4; ++nt) {
            int n = nt * 16 + lr;
            int c0 = wv * 32 + ct * 16 + lg * 4;
            bf16x4 o;
#pragma unroll
            for (int r = 0; r < 4; ++r) {
                float v = (float)resr[ct][nt][r] + bp[ct][r] + pacc[ct][nt][r];
                o[r] = (bf16)v;
                if constexpr (STAGE == 1) {
                    ps[ct][r] += v;
                    pm[ct][r] = fmaxf(pm[ct][r], v);
                }
            }
            size_t pix;
            if constexpr (STAGE == 0) {
                int ph = wr * 8 + (n >> 3), pw = wc * 8 + (n & 7);
                int gw = ((ph & 31) << 5) + (pw & 31);
                int nn = ((ph >> 5) << 3) + (pw >> 5);
                pix = (size_t)b * 65536 + (size_t)gw * 64 + nn;
            } else {
                pix = (size_t)b * 65536 + (size_t)(wr * 32 + wc) * 64 + n;
            }
            *(bf16x4*)(xout + pix * 128 + c0) = o;
        }

    if constexpr (STAGE == 1) {
        const int w = blk & 1023;
        float* prow_s = psum + (size_t)w * 512 + b * 128;
        float* prow_m = pmax + (size_t)w * 512 + b * 128;
#pragma unroll
        for (int ct = 0; ct < 2; ++ct) {
            f32x4 sv, mv;
#pragma unroll
            for (int r = 0; r < 4; ++r) {
                float s = ps[ct][r], m = pm[ct][r];
#pragma unroll
                for (int o = 1; o < 16; o <<= 1) {
                    s += __shfl_xor(s, o);
                    m = fmaxf(m, __shfl_xor(m, o));
                }
                sv[r] = s; mv[r] = m;
            }
            if (lr == 0) {
                int cbase = wv * 32 + ct * 16 + lg * 4;
                *(f32x4*)&prow_s[cbase] = sv;     // 16B vector store (full lines)
                *(f32x4*)&prow_m[cbase] = mv;
            }
        }
    }
}

// ---- reduce pooling partials: avg/mx[b*128+c] over 1024 windows ----
__global__ __launch_bounds__(64) void reduce_kernel(const float* __restrict__ psum,
                                                    const float* __restrict__ pmax,
                                                    float* __restrict__ avg,
                                                    float* __restrict__ mx)
{
    int bc = blockIdx.x;        // 0..511
    int t = threadIdx.x;        // 0..63
    float s = 0.f, m = -1e30f;
#pragma unroll
    for (int k = 0; k < 16; ++k) {
        size_t w = t + k * 64;
        s += psum[w * 512 + bc];
        m = fmaxf(m, pmax[w * 512 + bc]);
    }
#pragma unroll
    for (int o = 1; o < 64; o <<= 1) {
        s += __shfl_xor(s, o);
        m = fmaxf(m, __shfl_xor(m, o));
    }
    if (t == 0) { avg[bc] = s * (1.f / 65536.f); mx[bc] = m; }
}

// ---- gate = sigmoid( (relu(avg@W1)+relu(mx@W1)) @ W2 ) ----
__global__ void gate_kernel(const float* __restrict__ avg, const float* __restrict__ mxp,
                            const float* __restrict__ w1, const float* __restrict__ w2,
                            float* __restrict__ gate)
{
    __shared__ float la[512], lm[512], s1[512];
    int t = threadIdx.x;
    la[t] = avg[t];
    lm[t] = mxp[t];
    __syncthreads();
    int b = t >> 7, co = t & 127;
    float a1 = 0.f, m1 = 0.f;
    for (int c = 0; c < 128; ++c) {
        float w = w1[c * 128 + co];
        a1 += la[b * 128 + c] * w;
        m1 += lm[b * 128 + c] * w;
    }
    s1[t] = fmaxf(a1, 0.f) + fmaxf(m1, 0.f);
    __syncthreads();
    float g = 0.f;
    for (int c = 0; c < 128; ++c) g += s1[b * 128 + c] * w2[c * 128 + co];
    gate[t] = 1.f / (1.f + __expf(-g));
}

// ---- k4: x2 (grid-major bf16) * gate -> out NCHW fp32 (tiled LDS transpose) ----
__global__ __launch_bounds__(256) void tout_kernel(const bf16* __restrict__ x2,
                                                   const float* __restrict__ gate,
                                                   float* __restrict__ out)
{
    __shared__ float s[128 * 68];
    __shared__ float sg[128];
    const int blk = blockIdx.x;            // b*1024 + chunk(64px within one row)
    const int b = blk >> 10;
    const int chunk = blk & 1023;
    const int ph = chunk >> 2, pw0 = (chunk & 3) * 64;
    const int gwb = (ph & 31) << 5;
    const int nb  = ((ph >> 5) << 3) + (pw0 >> 5);
    const int t = threadIdx.x;
    if (t < 128) sg[t] = gate[b * 128 + t];
    __syncthreads();
    const bf16* base = x2 + (size_t)b * 65536 * 128;
#pragma unroll
    for (int i = 0; i < 4; ++i) {
        int idx8 = t + i * 256;            // 0..1023 = 64px * 16 chunks
        int px = idx8 >> 4, c8 = idx8 & 15;
        size_t pi = (size_t)(gwb + (px & 31)) * 64 + nb + (px >> 5);
        bf16x8 v = *(const bf16x8*)(base + pi * 128 + c8 * 8);
        int pxs = px ^ ((c8 & 7) << 3);
#pragma unroll
        for (int j = 0; j < 8; ++j) {
            int c = c8 * 8 + j;
            s[c * 68 + pxs] = (float)v[j] * sg[c];
        }
    }
    __syncthreads();
    int cg = t >> 4, pl = (t & 15) * 4;
#pragma unroll
    for (int i = 0; i < 8; ++i) {
        int c = cg + i * 16;
        int pp = pl ^ (((c >> 3) & 7) << 3);
        f32x4 w = *(const f32x4*)&s[c * 68 + pp];
        *(f32x4*)&out[((size_t)(b * 128 + c)) * 65536 + ph * 256 + pw0 + pl] = w;
    }
}

extern "C" void kernel_launch(void* const* d_in, const int* in_sizes, int n_in,
                              void* d_out, int out_size, void* d_ws, size_t ws_size,
                              hipStream_t stream)
{
    const float* x      = (const float*)d_in[0];
    const float* w_qkv  = (const float*)d_in[1];
    const float* b_qkv  = (const float*)d_in[2];
    const float* w_proj = (const float*)d_in[3];
    const float* b_proj = (const float*)d_in[4];
    const float* rpb    = (const float*)d_in[5];
    const float* cf_w1  = (const float*)d_in[6];
    const float* cf_w2  = (const float*)d_in[7];
    float* out = (float*)d_out;

    char* ws = (char*)d_ws;
    // ws[0:64MB] = xT (bf16 linear NHWC, dead after attn<0>)
    //            = x2 (bf16 grid-major, written by attn<1>, read by tout)
    bf16* xT = (bf16*)ws;
    bf16* x2 = (bf16*)ws;
    char* tail = ws + 67108864;                      // 64 MB
    bf16*  wqkvT  = (bf16*)tail;                     // 96 KB
    bf16*  wprojT = (bf16*)(tail + 98304);           // 32 KB
    float* psum   = (float*)(tail + 131072);         // 2 MB  (1024 windows x 512)
    float* pmax   = (float*)(tail + 131072 + 2097152);   // 2 MB
    float* avg    = (float*)(tail + 131072 + 4194304);   // 2 KB
    float* mxp    = (float*)(tail + 131072 + 4196352);   // 2 KB
    float* gate   = (float*)(tail + 131072 + 4198400);   // 2 KB
    bf16*  biasC  = (bf16*)(tail + 131072 + 4200448);    // 32 KB
    bf16*  x1T    = (bf16*)d_out;                    // grid-major bf16, 64MB, dead after attn<1>

    tin_kernel<<<4096, 256, 0, stream>>>(x, xT);
    wconv_kernel<<<256, 256, 0, stream>>>(w_qkv, w_proj, rpb, wqkvT, wprojT, biasC);
    attn_kernel<0><<<4096, 256, 0, stream>>>(xT,  x1T, wqkvT, wprojT,
                                             b_qkv, b_proj, biasC, nullptr, nullptr);
    attn_kernel<1><<<4096, 256, 0, stream>>>(x1T, x2,  wqkvT, wprojT,
                                             b_qkv, b_proj, biasC, psum, pmax);
    reduce_kernel<<<512, 64, 0, stream>>>(psum, pmax, avg, mxp);
    gate_kernel<<<1, 512, 0, stream>>>(avg, mxp, cf_w1, cf_w2, gate);
    tout_kernel<<<4096, 256, 0, stream>>>(x2, gate, out);
}